// Round 13
// baseline (300.248 us; speedup 1.0000x reference)
//
#include <hip/hip_runtime.h>
#include <hip/hip_bf16.h>

#define B_ 2
#define T_ 2048
#define D_ 2048
#define H_ 16
#define HD_ 128
#define M_ 4096

typedef __attribute__((ext_vector_type(8))) short short8;
typedef __attribute__((ext_vector_type(8))) __bf16 bf16x8;
typedef __attribute__((ext_vector_type(4))) float f32x4;
typedef __attribute__((ext_vector_type(4))) unsigned uint32x4;

__device__ __forceinline__ short f2bf(float f) {
  unsigned u = __builtin_bit_cast(unsigned, f);
  u += 0x7fffu + ((u >> 16) & 1u);
  return (short)(u >> 16);
}

__device__ __forceinline__ unsigned cvtpk(float lo, float hi) {
  unsigned r;
  asm("v_cvt_pk_bf16_f32 %0, %1, %2" : "=v"(r) : "v"(lo), "v"(hi));
  return r;
}

__device__ __forceinline__ float ex2(float x) {
  float r;
  asm("v_exp_f32 %0, %1" : "=v"(r) : "v"(x));
  return r;
}

__device__ __forceinline__ void gl_lds16(const void* g, void* l) {
  __builtin_amdgcn_global_load_lds(
      (const __attribute__((address_space(1))) unsigned int*)g,
      (__attribute__((address_space(3))) unsigned int*)l, 16, 0, 0);
}

__device__ __forceinline__ f32x4 mfma_bf16(short8 a, short8 b, f32x4 c) {
  return __builtin_amdgcn_mfma_f32_16x16x32_bf16(
      __builtin_bit_cast(bf16x8, a), __builtin_bit_cast(bf16x8, b), c, 0, 0, 0);
}

__device__ __forceinline__ float2 sw16f(float x) {
  float a = x, bv;
  asm("v_mov_b32 %0, %1" : "=v"(bv) : "v"(x));
  asm("v_permlane16_swap_b32 %0, %1" : "+v"(a), "+v"(bv));
  return make_float2(a, bv);
}
__device__ __forceinline__ float2 sw32f(float x) {
  float a = x, bv;
  asm("v_mov_b32 %0, %1" : "=v"(bv) : "v"(x));
  asm("v_permlane32_swap_b32 %0, %1" : "+v"(a), "+v"(bv));
  return make_float2(a, bv);
}
__device__ __forceinline__ void sw16u(unsigned x, unsigned& e, unsigned& o) {
  unsigned a = x, bv;
  asm("v_mov_b32 %0, %1" : "=v"(bv) : "v"(x));
  asm("v_permlane16_swap_b32 %0, %1" : "+v"(a), "+v"(bv));
  e = a; o = bv;
}
__device__ __forceinline__ void pl32u(unsigned& a, unsigned& b) {
  asm("v_permlane32_swap_b32 %0, %1" : "+v"(a), "+v"(b));
}

// ---------------- cast x -> bf16 ----------------
__global__ void cast_f32_bf16(const float* __restrict__ in, short* __restrict__ out, int n4) {
  int i = blockIdx.x * blockDim.x + threadIdx.x;
  int stride = gridDim.x * blockDim.x;
  for (; i < n4; i += stride) {
    float4 v = ((const float4*)in)[i];
    short4 s;
    s.x = f2bf(v.x); s.y = f2bf(v.y); s.z = f2bf(v.z); s.w = f2bf(v.w);
    ((short4*)out)[i] = s;
  }
}

// ---------------- 4x W (K,N) f32 -> Wt (N,K) bf16, fused ----------------
__global__ void transpose_cast_w4(const float* __restrict__ Wq, const float* __restrict__ Wk,
                                  const float* __restrict__ Wv, const float* __restrict__ Wo,
                                  short* __restrict__ wqkv, short* __restrict__ wo) {
  __shared__ float t[32][33];
  int z = blockIdx.z;
  const float* W = z == 0 ? Wq : z == 1 ? Wk : z == 2 ? Wv : Wo;
  short* dst = z < 3 ? wqkv + (size_t)z * D_ * D_ : wo;
  int n0 = blockIdx.x * 32, k0 = blockIdx.y * 32;
  int tx = threadIdx.x, ty = threadIdx.y;
#pragma unroll
  for (int j = 0; j < 4; ++j)
    t[ty + j * 8][tx] = W[(size_t)(k0 + ty + j * 8) * D_ + n0 + tx];
  __syncthreads();
#pragma unroll
  for (int j = 0; j < 4; ++j)
    dst[(size_t)(n0 + ty + j * 8) * D_ + k0 + tx] = f2bf(t[tx][ty + j * 8]);
}

// ---------------- 256x192 QKV GEMM: A in LDS, B direct from L2 to regs ----------------
// 512 thr = 8 waves (2M x 4N), per-wave 128x48 (acc[8][3]). BK=64 (two kh).
// LDS 64 KB = A only: [buf][kh][256 rows x 32k], rows 64B, swizzle ((row>>1)&3)<<4
// via inverse-swizzled source. B-fragments load global->regs (L2-resident panel,
// n-major XCD chunking = 3 MB/XCD), double-buffered one K-tile ahead.
// Per phase: 8 ds_read (A) + 24 MFMA; stage ledger A(t+1,1)@ph0, A(t+2,0)@ph1,
// B(t+1)@ph0; vmcnt(10) at both phase ends (10 = 2+2+6 in flight; every A half
// retires >=1 tile before its reads; tail re-stages idempotent).
__global__ __launch_bounds__(512, 2) void gemm_qkv(
    const short* __restrict__ A, const short* __restrict__ Bt,
    const float* __restrict__ b0, const float* __restrict__ b1,
    const float* __restrict__ b2,
    short* __restrict__ q_o, short* __restrict__ k_o,
    float* __restrict__ kf_o, float* __restrict__ vf_o,
    short* __restrict__ vt_o) {
  __shared__ __attribute__((aligned(16))) char lds[2][2][16384];  // 64 KB
  const int K = D_, NT = K / 64;

  int d = blockIdx.x;
  int lg = (d & 7) * 64 + (d >> 3);          // 512 = 8 XCD x 64, bijective
  int m0 = (lg & 15) * 256, n0 = (lg >> 4) * 192;

  int tid = threadIdx.x, lane = tid & 63, wid = tid >> 6;
  int wm = wid >> 2, wn = wid & 3;
  int lr = lane & 15, g = lane >> 4;

  // A staging: 2 loads (rows tid>>2, +128), 64B rows, swizzle ((row>>1)&3)<<4
  int rowA = tid >> 2;
  int cA = ((((tid & 3) << 4) ^ (((rowA >> 1) & 3) << 4)) >> 1);
  const short* aS = A + (size_t)(m0 + rowA) * K + cA;

  auto stageA = [&](int ts, int kh) {
    char* dst = &lds[ts & 1][kh][0] + tid * 16;
    const short* s = aS + ts * 64 + kh * 32;
    gl_lds16(s, dst);
    gl_lds16(s + (size_t)128 * K, dst + 8192);
  };

  // B fragment bases (global): lane reads row n0+wn*48+ni*16+lr, k-seg g*8
  const short* bb0 = Bt + (size_t)(n0 + wn * 48 + lr) * K + g * 8;
  const short* bb1 = bb0 + (size_t)16 * K;
  const short* bb2 = bb0 + (size_t)32 * K;

  short8 B0[3][2], B1[3][2];
  auto loadB = [&](int ts, short8 (&Bn)[3][2]) {
    int off = ts * 64;
#pragma unroll
    for (int kh = 0; kh < 2; ++kh) {
      Bn[0][kh] = *(const short8*)(bb0 + off + kh * 32);
      Bn[1][kh] = *(const short8*)(bb1 + off + kh * 32);
      Bn[2][kh] = *(const short8*)(bb2 + off + kh * 32);
    }
  };

  int swzA = (g * 16) ^ (((lr >> 1) & 3) << 4);
  int aoff = (wm * 128 + lr) * 64 + swzA;   // + mi*1024 within a 16 KB half

  f32x4 acc[8][3] = {};

  // prologue: A(0,0), A(0,1), A(1,0) staged; B(0) loaded (stays in flight)
  stageA(0, 0); stageA(0, 1); stageA(1, 0);
  loadB(0, B0);
  asm volatile("s_waitcnt vmcnt(6)" ::: "memory");
  __builtin_amdgcn_s_barrier();
  __builtin_amdgcn_sched_barrier(0);

  auto TILE = [&](int t, short8 (&Bc)[3][2], short8 (&Bn)[3][2]) {
    const char* base0 = &lds[t & 1][0][0];
    const char* base1 = &lds[t & 1][1][0];
    int t1 = (t + 1 < NT) ? t + 1 : NT - 1;
    int t2 = (t + 2 < NT) ? t + 2 : NT - 1;
    short8 afr[8];

    // ---- ph0: kh0 ----
#pragma unroll
    for (int mi = 0; mi < 8; ++mi) afr[mi] = *(const short8*)(base0 + aoff + mi * 1024);
    stageA(t1, 1);
    loadB(t1, Bn);
    __builtin_amdgcn_s_setprio(1);
#pragma unroll
    for (int mi = 0; mi < 8; ++mi)
#pragma unroll
      for (int ni = 0; ni < 3; ++ni)
        acc[mi][ni] = mfma_bf16(afr[mi], Bc[ni][0], acc[mi][ni]);
    __builtin_amdgcn_s_setprio(0);
    asm volatile("s_waitcnt vmcnt(10)" ::: "memory");
    __builtin_amdgcn_s_barrier();
    __builtin_amdgcn_sched_barrier(0);

    // ---- ph1: kh1 ----
#pragma unroll
    for (int mi = 0; mi < 8; ++mi) afr[mi] = *(const short8*)(base1 + aoff + mi * 1024);
    stageA(t2, 0);
    __builtin_amdgcn_s_setprio(1);
#pragma unroll
    for (int mi = 0; mi < 8; ++mi)
#pragma unroll
      for (int ni = 0; ni < 3; ++ni)
        acc[mi][ni] = mfma_bf16(afr[mi], Bc[ni][1], acc[mi][ni]);
    __builtin_amdgcn_s_setprio(0);
    asm volatile("s_waitcnt vmcnt(10)" ::: "memory");
    __builtin_amdgcn_s_barrier();
    __builtin_amdgcn_sched_barrier(0);
  };

#pragma unroll 1
  for (int t = 0; t < NT; t += 2) {
    TILE(t, B0, B1);
    TILE(t + 1, B1, B0);
  }

  // epilogue: per-ni region select (16-col groups never span q/k/v regions)
#pragma unroll
  for (int ni = 0; ni < 3; ++ni) {
    int gcb = n0 + wn * 48 + ni * 16;
    int region = gcb >> 11;
    int nc = (gcb & 2047) + lr;
    int hh = nc >> 7, hd = nc & 127;
    const float* bias = region == 0 ? b0 : region == 1 ? b1 : b2;
    float bv = bias[nc];
#pragma unroll
    for (int mi = 0; mi < 8; ++mi) {
      int gr0 = m0 + wm * 128 + mi * 16 + (g << 2);
      int bb = gr0 >> 11, tt0 = gr0 & 2047;
      size_t hbase = (size_t)(bb * H_ + hh);
      float v0 = acc[mi][ni][0] + bv;
      float v1 = acc[mi][ni][1] + bv;
      float v2 = acc[mi][ni][2] + bv;
      float v3 = acc[mi][ni][3] + bv;
      size_t ib = (hbase * T_ + tt0) * HD_ + hd;
      if (region == 0) {
        q_o[ib] = f2bf(v0); q_o[ib + HD_] = f2bf(v1);
        q_o[ib + 2 * HD_] = f2bf(v2); q_o[ib + 3 * HD_] = f2bf(v3);
      } else if (region == 1) {
        k_o[ib] = f2bf(v0); k_o[ib + HD_] = f2bf(v1);
        k_o[ib + 2 * HD_] = f2bf(v2); k_o[ib + 3 * HD_] = f2bf(v3);
        kf_o[ib] = v0; kf_o[ib + HD_] = v1;
        kf_o[ib + 2 * HD_] = v2; kf_o[ib + 3 * HD_] = v3;
      } else {
        vf_o[ib] = v0; vf_o[ib + HD_] = v1;
        vf_o[ib + 2 * HD_] = v2; vf_o[ib + 3 * HD_] = v3;
        short4 s4;
        s4.x = f2bf(v0); s4.y = f2bf(v1); s4.z = f2bf(v2); s4.w = f2bf(v3);
        *(short4*)&vt_o[(hbase * HD_ + hd) * T_ + tt0] = s4;
      }
    }
  }
}

// ---------------- ring-4 GEMM (Wo): C(M,2048) = A * Bt + bias, f32 out ----------------
__global__ __launch_bounds__(256, 2) void gemm_rb(
    const short* __restrict__ A, const short* __restrict__ Bt,
    const float* __restrict__ b0, float* __restrict__ f_o) {
  __shared__ __attribute__((aligned(16))) short lds[4][2][4096];
  const int K = D_, NT = K / 32;

  int nx = gridDim.x, nwg = nx * gridDim.y;
  int d = blockIdx.y * nx + blockIdx.x;
  int cpx = nwg >> 3;
  int lg = (d & 7) * cpx + (d >> 3);
  int m0 = (lg / nx) * 128, n0 = (lg % nx) * 128;

  int tid = threadIdx.x, lane = tid & 63, w = tid >> 6;
  int wm = w >> 1, wn = w & 1;
  int lr = lane & 15, g = lane >> 4;

  int o1 = tid * 16, o2 = 4096 + tid * 16;
  int row1 = tid >> 2, row2 = 64 + row1;
  int cb = (tid & 3) << 4;
  int c1 = (cb ^ (((row1 >> 1) & 3) << 4)) >> 1;
  int c2 = (cb ^ (((row2 >> 1) & 3) << 4)) >> 1;
  const short* aS1 = A + (size_t)(m0 + row1) * K + c1;
  const short* aS2 = A + (size_t)(m0 + row2) * K + c2;
  const short* bS1 = Bt + (size_t)(n0 + row1) * K + c1;
  const short* bS2 = Bt + (size_t)(n0 + row2) * K + c2;

  int aoff[4], boff[4];
#pragma unroll
  for (int i = 0; i < 4; ++i) {
    int ra = wm * 64 + i * 16 + lr;
    aoff[i] = ra * 64 + ((g * 16) ^ (((ra >> 1) & 3) << 4));
    int rb = wn * 64 + i * 16 + lr;
    boff[i] = rb * 64 + ((g * 16) ^ (((rb >> 1) & 3) << 4));
  }

  f32x4 acc[4][4] = {};

#pragma unroll
  for (int s = 0; s < 3; ++s) {
    char* la = (char*)&lds[s][0][0];
    char* lb = (char*)&lds[s][1][0];
    gl_lds16(aS1 + s * 32, la + o1);
    gl_lds16(aS2 + s * 32, la + o2);
    gl_lds16(bS1 + s * 32, lb + o1);
    gl_lds16(bS2 + s * 32, lb + o2);
  }
  asm volatile("s_waitcnt vmcnt(8)" ::: "memory");
  __builtin_amdgcn_s_barrier();
  __builtin_amdgcn_sched_barrier(0);

#pragma unroll 1
  for (int t4 = 0; t4 < NT; t4 += 4) {
#pragma unroll
    for (int p = 0; p < 4; ++p) {
      int t = t4 + p;
      {
        int ts = (t + 3 < NT) ? t + 3 : NT - 1;
        char* la = (char*)&lds[(p + 3) & 3][0][0];
        char* lb = (char*)&lds[(p + 3) & 3][1][0];
        gl_lds16(aS1 + ts * 32, la + o1);
        gl_lds16(aS2 + ts * 32, la + o2);
        gl_lds16(bS1 + ts * 32, lb + o1);
        gl_lds16(bS2 + ts * 32, lb + o2);
      }
      const char* la = (const char*)&lds[p][0][0];
      const char* lb = (const char*)&lds[p][1][0];
      short8 af[4], bfv[4];
#pragma unroll
      for (int i = 0; i < 4; ++i) {
        af[i] = *(const short8*)(la + aoff[i]);
        bfv[i] = *(const short8*)(lb + boff[i]);
      }
      __builtin_amdgcn_s_setprio(1);
#pragma unroll
      for (int mi = 0; mi < 4; ++mi)
#pragma unroll
        for (int ni = 0; ni < 4; ++ni)
          acc[mi][ni] = mfma_bf16(af[mi], bfv[ni], acc[mi][ni]);
      __builtin_amdgcn_s_setprio(0);
      asm volatile("s_waitcnt vmcnt(8)" ::: "memory");
      __builtin_amdgcn_s_barrier();
      __builtin_amdgcn_sched_barrier(0);
    }
  }

#pragma unroll
  for (int mi = 0; mi < 4; ++mi) {
#pragma unroll
    for (int ni = 0; ni < 4; ++ni) {
      int gr0 = m0 + wm * 64 + mi * 16 + (g << 2);
      int gc = n0 + wn * 64 + ni * 16 + lr;
      float bv = b0[gc];
#pragma unroll
      for (int r = 0; r < 4; ++r)
        f_o[(size_t)(gr0 + r) * D_ + gc] = acc[mi][ni][r] + bv;
    }
  }
}

// ---------------- causal flash attention (v7: LPT grid, exp2 softmax) ----------------
__global__ __launch_bounds__(256, 2) void attn_fwd(
    const short* __restrict__ qb, const short* __restrict__ kb,
    const short* __restrict__ vtb, short* __restrict__ aob) {
  __shared__ __attribute__((aligned(16))) char kvlds[2][16384];

  int d = blockIdx.x;
  int bh = d & 31;
  int qt = 31 - (d >> 5);          // big jobs dispatch first
  int tid = threadIdx.x, w = tid >> 6, lane = tid & 63;
  int lr = lane & 15, g = lane >> 4;
  const short* Q  = qb  + (size_t)bh * T_ * HD_;
  const short* Kp = kb  + (size_t)bh * T_ * HD_;
  const short* Vt = vtb + (size_t)bh * HD_ * T_;
  const float scale2 = 0.12751879202f;  // (1/sqrt(128)) * log2(e)
  int b = bh >> 4, h = bh & 15;
  bool hi16 = (lane & 16) != 0;

  int oA = ((2 * w + 0) * 64 + lane) * 16;
  int oB = ((2 * w + 1) * 64 + lane) * 16;
  int rKA = oA >> 8, rKB = oB >> 8;
  size_t skA = (size_t)rKA * HD_ + (((oA & 255) ^ ((rKA & 7) << 4)) >> 1);
  size_t skB = (size_t)rKB * HD_ + (((oB & 255) ^ ((rKB & 7) << 4)) >> 1);
  int rVA = oA >> 6, rVB = oB >> 6;
  size_t svA = (size_t)rVA * T_ + (((oA & 63) ^ (((rVA >> 1) & 3) << 4)) >> 1);
  size_t svB = (size_t)rVB * T_ + (((oB & 63) ^ (((rVB >> 1) & 3) << 4)) >> 1);

  int q0 = qt * 64 + w * 16;
  int ntiles = 2 * qt + 2;

  {
    char* kd = &kvlds[0][0];
    char* vd = &kvlds[0][8192];
    gl_lds16(Kp + skA, kd + oA);
    gl_lds16(Kp + skB, kd + oB);
    gl_lds16(Vt + svA, vd + oA);
    gl_lds16(Vt + svB, vd + oB);
  }

  short8 qf[4];
#pragma unroll
  for (int kk = 0; kk < 4; ++kk)
    qf[kk] = *(const short8*)&Q[(size_t)(q0 + lr) * HD_ + kk * 32 + g * 8];

  f32x4 o[8] = {};
  float mrow = -1e30f, lrow = 0.f;
  __syncthreads();

#pragma unroll 1
  for (int t = 0; t < ntiles; ++t) {
    int kv0 = t * 32, buf = t & 1;
    if (t + 1 < ntiles) {
      char* kd = &kvlds[buf ^ 1][0];
      char* vd = &kvlds[buf ^ 1][8192];
      const short* Kn = Kp + (size_t)(kv0 + 32) * HD_;
      const short* Vn = Vt + (kv0 + 32);
      gl_lds16(Kn + skA, kd + oA);
      gl_lds16(Kn + skB, kd + oB);
      gl_lds16(Vn + svA, vd + oA);
      gl_lds16(Vn + svB, vd + oB);
    }
    if (kv0 < q0 + 16) {
      const char* kb_ = &kvlds[buf][0];
      const char* vb_ = &kvlds[buf][8192];
      short8 kf0[4], kf1[4], vf[8];
#pragma unroll
      for (int kk = 0; kk < 4; ++kk) {
        int cs = (kk * 64 + g * 16) ^ ((lr & 7) << 4);
        kf0[kk] = *(const short8*)(kb_ + (lr * 256 + cs));
        kf1[kk] = *(const short8*)(kb_ + ((16 + lr) * 256 + cs));
      }
#pragma unroll
      for (int f = 0; f < 8; ++f)
        vf[f] = *(const short8*)(vb_ + ((f * 16 + lr) * 64 +
                 ((g * 16) ^ (((lr >> 1) & 3) << 4))));

      f32x4 s0 = {}, s1 = {};
      __builtin_amdgcn_s_setprio(1);
#pragma unroll
      for (int kk = 0; kk < 4; ++kk) {
        s0 = mfma_bf16(kf0[kk], qf[kk], s0);
        s1 = mfma_bf16(kf1[kk], qf[kk], s1);
      }
      __builtin_amdgcn_s_setprio(0);

      float vv[8];
#pragma unroll
      for (int r = 0; r < 4; ++r) {
        vv[r] = s0[r] * scale2;
        vv[4 + r] = s1[r] * scale2;
      }
      if (kv0 + 31 > q0) {
        int qrow = q0 + lr;
#pragma unroll
        for (int r = 0; r < 4; ++r) {
          if (kv0 + 4 * g + r > qrow) vv[r] = -1e30f;
          if (kv0 + 16 + 4 * g + r > qrow) vv[4 + r] = -1e30f;
        }
      }

      float pm = vv[0];
#pragma unroll
      for (int i = 1; i < 8; ++i) pm = fmaxf(pm, vv[i]);
      { float2 tpm = sw32f(pm); pm = fmaxf(tpm.x, tpm.y); }
      { float2 tpm = sw16f(pm); pm = fmaxf(tpm.x, tpm.y); }

      bool rescale = !__all(pm - mrow <= 11.54f);
      float alpha = 1.0f;
      if (rescale) {
        float mnew = fmaxf(mrow, pm);
        alpha = ex2(mrow - mnew);
        mrow = mnew;
      }

      float p[8];
      float rs = 0.f;
#pragma unroll
      for (int i = 0; i < 8; ++i) { p[i] = ex2(vv[i] - mrow); rs += p[i]; }
      { float2 trs = sw32f(rs); rs = trs.x + trs.y; }
      { float2 trs = sw16f(rs); rs = trs.x + trs.y; }
      lrow = (rescale ? lrow * alpha : lrow) + rs;

      if (rescale) {
        float alr[4];
#pragma unroll
        for (int r = 0; r < 4; ++r) alr[r] = __shfl(alpha, 4 * g + r);
#pragma unroll
        for (int f = 0; f < 8; ++f)
#pragma unroll
          for (int r = 0; r < 4; ++r) o[f][r] *= alr[r];
      }

      unsigned w0 = cvtpk(p[0], p[1]), w1 = cvtpk(p[2], p[3]);
      unsigned w2 = cvtpk(p[4], p[5]), w3 = cvtpk(p[6], p[7]);
      unsigned e0, od0, e1, od1, e2, od2, e3, od3;
      sw16u(w0, e0, od0); sw16u(w1, e1, od1);
      sw16u(w2, e2, od2); sw16u(w3, e3, od3);
      unsigned F0 = e0,  S0 = e2;  pl32u(F0, S0);
      unsigned F1 = e1,  S1 = e3;  pl32u(F1, S1);
      unsigned F2 = od0, S2 = od2; pl32u(F2, S2);
      unsigned F3 = od1, S3 = od3; pl32u(F3, S3);
      uint32x4 paw = { hi16 ? S0 : F0, hi16 ? S1 : F1,
                       hi16 ? S2 : F2, hi16 ? S3 : F3 };
      short8 pa = __builtin_bit_cast(short8, paw);

      __builtin_amdgcn_s_setprio(1);
#pragma unroll
      for (int f = 0; f < 8; ++f) o[f] = mfma_bf16(pa, vf[f], o[f]);
      __builtin_amdgcn_s_setprio(0);
    }
    __syncthreads();
  }

  float inv = 1.0f / lrow;
  float invr[4];
#pragma unroll
  for (int r = 0; r < 4; ++r) invr[r] = __shfl(inv, 4 * g + r);
#pragma unroll
  for (int r = 0; r < 4; ++r) {
    int q = q0 + 4 * g + r;
    size_t rowoff = ((size_t)(b * T_ + q)) * D_ + h * HD_;
#pragma unroll
    for (int f = 0; f < 8; ++f)
      aob[rowoff + f * 16 + lr] = f2bf(o[f][r] * invr[r]);
  }
}

extern "C" void kernel_launch(void* const* d_in, const int* in_sizes, int n_in,
                              void* d_out, int out_size, void* d_ws, size_t ws_size,
                              hipStream_t stream) {
  const float* x  = (const float*)d_in[0];
  const float* Wq = (const float*)d_in[1];
  const float* bq = (const float*)d_in[2];
  const float* Wk = (const float*)d_in[3];
  const float* bk = (const float*)d_in[4];
  const float* Wv = (const float*)d_in[5];
  const float* bv = (const float*)d_in[6];
  const float* Wo = (const float*)d_in[7];
  const float* bo = (const float*)d_in[8];
  float* out  = (float*)d_out;
  float* kout = out + (size_t)M_ * D_;
  float* vout = kout + (size_t)M_ * D_;

  char* ws = (char*)d_ws;
  auto alloc = [&](size_t bytes) {
    char* p = ws;
    ws += (bytes + 255) & ~(size_t)255;
    return p;
  };
  short* xb    = (short*)alloc((size_t)M_ * D_ * 2);
  short* wqkvT = (short*)alloc((size_t)3 * D_ * D_ * 2);
  short* woT   = (short*)alloc((size_t)D_ * D_ * 2);
  short* qb    = (short*)alloc((size_t)M_ * D_ * 2);
  short* kb    = (short*)alloc((size_t)M_ * D_ * 2);
  short* vtb   = (short*)alloc((size_t)M_ * D_ * 2);
  short* aob = xb;  // reuse: xb dead after QKV GEMM

  cast_f32_bf16<<<2048, 256, 0, stream>>>(x, xb, M_ * D_ / 4);
  dim3 tb(32, 8);
  transpose_cast_w4<<<dim3(64, 64, 4), tb, 0, stream>>>(Wq, Wk, Wv, Wo, wqkvT, woT);

  gemm_qkv<<<512, 512, 0, stream>>>(xb, wqkvT, bq, bk, bv, qb, kb, kout, vout, vtb);
  attn_fwd<<<1024, 256, 0, stream>>>(qb, kb, vtb, aob);
  gemm_rb<<<dim3(16, 32), 256, 0, stream>>>(aob, woT, bo, out);
}

// Round 14
// 265.704 us; speedup vs baseline: 1.1300x; 1.1300x over previous
//
#include <hip/hip_runtime.h>
#include <hip/hip_bf16.h>

#define B_ 2
#define T_ 2048
#define D_ 2048
#define H_ 16
#define HD_ 128
#define M_ 4096

typedef __attribute__((ext_vector_type(8))) short short8;
typedef __attribute__((ext_vector_type(8))) __bf16 bf16x8;
typedef __attribute__((ext_vector_type(4))) float f32x4;
typedef __attribute__((ext_vector_type(4))) unsigned uint32x4;

__device__ __forceinline__ short f2bf(float f) {
  unsigned u = __builtin_bit_cast(unsigned, f);
  u += 0x7fffu + ((u >> 16) & 1u);
  return (short)(u >> 16);
}

__device__ __forceinline__ unsigned cvtpk(float lo, float hi) {
  unsigned r;
  asm("v_cvt_pk_bf16_f32 %0, %1, %2" : "=v"(r) : "v"(lo), "v"(hi));
  return r;
}

__device__ __forceinline__ float ex2(float x) {
  float r;
  asm("v_exp_f32 %0, %1" : "=v"(r) : "v"(x));
  return r;
}

__device__ __forceinline__ void gl_lds16(const void* g, void* l) {
  __builtin_amdgcn_global_load_lds(
      (const __attribute__((address_space(1))) unsigned int*)g,
      (__attribute__((address_space(3))) unsigned int*)l, 16, 0, 0);
}

__device__ __forceinline__ f32x4 mfma_bf16(short8 a, short8 b, f32x4 c) {
  return __builtin_amdgcn_mfma_f32_16x16x32_bf16(
      __builtin_bit_cast(bf16x8, a), __builtin_bit_cast(bf16x8, b), c, 0, 0, 0);
}

__device__ __forceinline__ float2 sw16f(float x) {
  float a = x, bv;
  asm("v_mov_b32 %0, %1" : "=v"(bv) : "v"(x));
  asm("v_permlane16_swap_b32 %0, %1" : "+v"(a), "+v"(bv));
  return make_float2(a, bv);
}
__device__ __forceinline__ float2 sw32f(float x) {
  float a = x, bv;
  asm("v_mov_b32 %0, %1" : "=v"(bv) : "v"(x));
  asm("v_permlane32_swap_b32 %0, %1" : "+v"(a), "+v"(bv));
  return make_float2(a, bv);
}
__device__ __forceinline__ void sw16u(unsigned x, unsigned& e, unsigned& o) {
  unsigned a = x, bv;
  asm("v_mov_b32 %0, %1" : "=v"(bv) : "v"(x));
  asm("v_permlane16_swap_b32 %0, %1" : "+v"(a), "+v"(bv));
  e = a; o = bv;
}
__device__ __forceinline__ void pl32u(unsigned& a, unsigned& b) {
  asm("v_permlane32_swap_b32 %0, %1" : "+v"(a), "+v"(b));
}

// ---------------- cast x -> bf16 ----------------
__global__ void cast_f32_bf16(const float* __restrict__ in, short* __restrict__ out, int n4) {
  int i = blockIdx.x * blockDim.x + threadIdx.x;
  int stride = gridDim.x * blockDim.x;
  for (; i < n4; i += stride) {
    float4 v = ((const float4*)in)[i];
    short4 s;
    s.x = f2bf(v.x); s.y = f2bf(v.y); s.z = f2bf(v.z); s.w = f2bf(v.w);
    ((short4*)out)[i] = s;
  }
}

// ---------------- 4x W (K,N) f32 -> Wt (N,K) bf16, fused ----------------
__global__ void transpose_cast_w4(const float* __restrict__ Wq, const float* __restrict__ Wk,
                                  const float* __restrict__ Wv, const float* __restrict__ Wo,
                                  short* __restrict__ wqkv, short* __restrict__ wo) {
  __shared__ float t[32][33];
  int z = blockIdx.z;
  const float* W = z == 0 ? Wq : z == 1 ? Wk : z == 2 ? Wv : Wo;
  short* dst = z < 3 ? wqkv + (size_t)z * D_ * D_ : wo;
  int n0 = blockIdx.x * 32, k0 = blockIdx.y * 32;
  int tx = threadIdx.x, ty = threadIdx.y;
#pragma unroll
  for (int j = 0; j < 4; ++j)
    t[ty + j * 8][tx] = W[(size_t)(k0 + ty + j * 8) * D_ + n0 + tx];
  __syncthreads();
#pragma unroll
  for (int j = 0; j < 4; ++j)
    dst[(size_t)(n0 + ty + j * 8) * D_ + k0 + tx] = f2bf(t[tx][ty + j * 8]);
}

// ---------------- 128x192 QKV GEMM: r8 inner pattern, 2 blocks/CU ----------------
// 256 thr = 4 waves (1M x 4N), per-wave 128x48 (acc[8][3]). BK=64 (two kh).
// LDS 80 KB = 2 buf x {A_kh0 8K | A_kh1 8K | B 24K} -> 2 blocks/CU (the lever:
// cross-block wave overlap hides per-block barrier/waitcnt drains, m114).
// Grid 1024 = 8 XCD x 128 bijective (4 n-panels/XCD = 3 MB B in L2), 2 rounds.
// ph0(t): read A(t,0)+B(t,0); stage A(t+1,1)+B(t+1); 24 MFMA; vmcnt(10); bar
// ph1(t): read A(t,1)+B(t,1); stage A(t+2,0);        24 MFMA; vmcnt(2);  bar
// Ledger: A(t,0)@ph1(t-2), A(t,1)+B(t)@ph0(t-1); vmcnt(2)@ph1(t-1) retires
// them before use; ph0's vmcnt(10) is a no-op fence. Tail re-stages idempotent.
__global__ __launch_bounds__(256, 2) void gemm_qkv(
    const short* __restrict__ A, const short* __restrict__ Bt,
    const float* __restrict__ b0, const float* __restrict__ b1,
    const float* __restrict__ b2,
    short* __restrict__ q_o, short* __restrict__ k_o,
    float* __restrict__ kf_o, float* __restrict__ vf_o,
    short* __restrict__ vt_o) {
  __shared__ __attribute__((aligned(16))) char lds[2][40960];  // 80 KB
  const int K = D_, NT = K / 64;

  int d = blockIdx.x;
  int lg = (d & 7) * 128 + (d >> 3);         // 1024 = 8 XCD x 128, bijective
  int m0 = (lg & 31) * 128, n0 = (lg >> 5) * 192;

  int tid = threadIdx.x, lane = tid & 63, wn = tid >> 6;
  int lr = lane & 15, g = lane >> 4;

  // A staging: 2 loads (rows tid>>2, +64), 64B rows, swizzle ((row>>1)&3)<<4
  int rowA = tid >> 2;
  int cA = ((((tid & 3) << 4) ^ (((rowA >> 1) & 3) << 4)) >> 1);
  const short* aS = A + (size_t)(m0 + rowA) * K + cA;
  // B staging: 6 loads (rows tid>>3 + 32j), 128B rows, swizzle ((row&7)<<4)
  int rowB = tid >> 3;
  int cB = ((((tid & 7) << 4) ^ ((rowB & 7) << 4)) >> 1);
  const short* bS = Bt + (size_t)(n0 + rowB) * K + cB;
  char* ldsb = (char*)lds;

  auto stageA = [&](int ts, int kh) {
    char* dst = ldsb + (ts & 1) * 40960 + kh * 8192 + tid * 16;
    const short* s = aS + ts * 64 + kh * 32;
    gl_lds16(s, dst);
    gl_lds16(s + (size_t)64 * K, dst + 4096);
  };
  auto stageB = [&](int ts) {
    char* dst = ldsb + (ts & 1) * 40960 + 16384 + tid * 16;
    const short* s = bS + ts * 64;
#pragma unroll
    for (int j = 0; j < 6; ++j)
      gl_lds16(s + (size_t)(j * 32) * K, dst + j * 4096);
  };

  int swzA = (g * 16) ^ (((lr >> 1) & 3) << 4);
  int aoff = lr * 64 + swzA;                                        // + mi*1024, kh*8192
  int boff0 = (wn * 48 + lr) * 128 + ((g * 16) ^ ((lr & 7) << 4));  // + ni*2048
  int boff1 = (wn * 48 + lr) * 128 + ((64 + g * 16) ^ ((lr & 7) << 4));

  f32x4 acc[8][3] = {};

  stageA(0, 0); stageA(0, 1); stageB(0); stageA(1, 0);
  asm volatile("s_waitcnt vmcnt(2)" ::: "memory");
  __builtin_amdgcn_s_barrier();
  __builtin_amdgcn_sched_barrier(0);

#pragma unroll 1
  for (int t = 0; t < NT; ++t) {
    const char* base = ldsb + (t & 1) * 40960;
    int t1 = (t + 1 < NT) ? t + 1 : NT - 1;
    int t2 = (t + 2 < NT) ? t + 2 : NT - 1;
    short8 afr[8], bfr[3];

    // ---- ph0: kh0 ----
#pragma unroll
    for (int mi = 0; mi < 8; ++mi) afr[mi] = *(const short8*)(base + aoff + mi * 1024);
#pragma unroll
    for (int ni = 0; ni < 3; ++ni) bfr[ni] = *(const short8*)(base + 16384 + boff0 + ni * 2048);
    stageA(t1, 1); stageB(t1);
    __builtin_amdgcn_s_setprio(1);
#pragma unroll
    for (int mi = 0; mi < 8; ++mi)
#pragma unroll
      for (int ni = 0; ni < 3; ++ni)
        acc[mi][ni] = mfma_bf16(afr[mi], bfr[ni], acc[mi][ni]);
    __builtin_amdgcn_s_setprio(0);
    asm volatile("s_waitcnt vmcnt(10)" ::: "memory");
    __builtin_amdgcn_s_barrier();
    __builtin_amdgcn_sched_barrier(0);

    // ---- ph1: kh1 ----
#pragma unroll
    for (int mi = 0; mi < 8; ++mi) afr[mi] = *(const short8*)(base + 8192 + aoff + mi * 1024);
#pragma unroll
    for (int ni = 0; ni < 3; ++ni) bfr[ni] = *(const short8*)(base + 16384 + boff1 + ni * 2048);
    stageA(t2, 0);
    __builtin_amdgcn_s_setprio(1);
#pragma unroll
    for (int mi = 0; mi < 8; ++mi)
#pragma unroll
      for (int ni = 0; ni < 3; ++ni)
        acc[mi][ni] = mfma_bf16(afr[mi], bfr[ni], acc[mi][ni]);
    __builtin_amdgcn_s_setprio(0);
    asm volatile("s_waitcnt vmcnt(2)" ::: "memory");
    __builtin_amdgcn_s_barrier();
    __builtin_amdgcn_sched_barrier(0);
  }

  // epilogue: per-ni region select (16-col groups never span q/k/v regions)
#pragma unroll
  for (int ni = 0; ni < 3; ++ni) {
    int gcb = n0 + wn * 48 + ni * 16;
    int region = gcb >> 11;
    int nc = (gcb & 2047) + lr;
    int hh = nc >> 7, hd = nc & 127;
    const float* bias = region == 0 ? b0 : region == 1 ? b1 : b2;
    float bv = bias[nc];
#pragma unroll
    for (int mi = 0; mi < 8; ++mi) {
      int gr0 = m0 + mi * 16 + (g << 2);
      int bb = gr0 >> 11, tt0 = gr0 & 2047;
      size_t hbase = (size_t)(bb * H_ + hh);
      float v0 = acc[mi][ni][0] + bv;
      float v1 = acc[mi][ni][1] + bv;
      float v2 = acc[mi][ni][2] + bv;
      float v3 = acc[mi][ni][3] + bv;
      size_t ib = (hbase * T_ + tt0) * HD_ + hd;
      if (region == 0) {
        q_o[ib] = f2bf(v0); q_o[ib + HD_] = f2bf(v1);
        q_o[ib + 2 * HD_] = f2bf(v2); q_o[ib + 3 * HD_] = f2bf(v3);
      } else if (region == 1) {
        k_o[ib] = f2bf(v0); k_o[ib + HD_] = f2bf(v1);
        k_o[ib + 2 * HD_] = f2bf(v2); k_o[ib + 3 * HD_] = f2bf(v3);
        kf_o[ib] = v0; kf_o[ib + HD_] = v1;
        kf_o[ib + 2 * HD_] = v2; kf_o[ib + 3 * HD_] = v3;
      } else {
        vf_o[ib] = v0; vf_o[ib + HD_] = v1;
        vf_o[ib + 2 * HD_] = v2; vf_o[ib + 3 * HD_] = v3;
        short4 s4;
        s4.x = f2bf(v0); s4.y = f2bf(v1); s4.z = f2bf(v2); s4.w = f2bf(v3);
        *(short4*)&vt_o[(hbase * HD_ + hd) * T_ + tt0] = s4;
      }
    }
  }
}

// ---------------- ring-4 GEMM (Wo): C(M,2048) = A * Bt + bias, f32 out ----------------
__global__ __launch_bounds__(256, 2) void gemm_rb(
    const short* __restrict__ A, const short* __restrict__ Bt,
    const float* __restrict__ b0, float* __restrict__ f_o) {
  __shared__ __attribute__((aligned(16))) short lds[4][2][4096];
  const int K = D_, NT = K / 32;

  int nx = gridDim.x, nwg = nx * gridDim.y;
  int d = blockIdx.y * nx + blockIdx.x;
  int cpx = nwg >> 3;
  int lg = (d & 7) * cpx + (d >> 3);
  int m0 = (lg / nx) * 128, n0 = (lg % nx) * 128;

  int tid = threadIdx.x, lane = tid & 63, w = tid >> 6;
  int wm = w >> 1, wn = w & 1;
  int lr = lane & 15, g = lane >> 4;

  int o1 = tid * 16, o2 = 4096 + tid * 16;
  int row1 = tid >> 2, row2 = 64 + row1;
  int cb = (tid & 3) << 4;
  int c1 = (cb ^ (((row1 >> 1) & 3) << 4)) >> 1;
  int c2 = (cb ^ (((row2 >> 1) & 3) << 4)) >> 1;
  const short* aS1 = A + (size_t)(m0 + row1) * K + c1;
  const short* aS2 = A + (size_t)(m0 + row2) * K + c2;
  const short* bS1 = Bt + (size_t)(n0 + row1) * K + c1;
  const short* bS2 = Bt + (size_t)(n0 + row2) * K + c2;

  int aoff[4], boff[4];
#pragma unroll
  for (int i = 0; i < 4; ++i) {
    int ra = wm * 64 + i * 16 + lr;
    aoff[i] = ra * 64 + ((g * 16) ^ (((ra >> 1) & 3) << 4));
    int rb = wn * 64 + i * 16 + lr;
    boff[i] = rb * 64 + ((g * 16) ^ (((rb >> 1) & 3) << 4));
  }

  f32x4 acc[4][4] = {};

#pragma unroll
  for (int s = 0; s < 3; ++s) {
    char* la = (char*)&lds[s][0][0];
    char* lb = (char*)&lds[s][1][0];
    gl_lds16(aS1 + s * 32, la + o1);
    gl_lds16(aS2 + s * 32, la + o2);
    gl_lds16(bS1 + s * 32, lb + o1);
    gl_lds16(bS2 + s * 32, lb + o2);
  }
  asm volatile("s_waitcnt vmcnt(8)" ::: "memory");
  __builtin_amdgcn_s_barrier();
  __builtin_amdgcn_sched_barrier(0);

#pragma unroll 1
  for (int t4 = 0; t4 < NT; t4 += 4) {
#pragma unroll
    for (int p = 0; p < 4; ++p) {
      int t = t4 + p;
      {
        int ts = (t + 3 < NT) ? t + 3 : NT - 1;
        char* la = (char*)&lds[(p + 3) & 3][0][0];
        char* lb = (char*)&lds[(p + 3) & 3][1][0];
        gl_lds16(aS1 + ts * 32, la + o1);
        gl_lds16(aS2 + ts * 32, la + o2);
        gl_lds16(bS1 + ts * 32, lb + o1);
        gl_lds16(bS2 + ts * 32, lb + o2);
      }
      const char* la = (const char*)&lds[p][0][0];
      const char* lb = (const char*)&lds[p][1][0];
      short8 af[4], bfv[4];
#pragma unroll
      for (int i = 0; i < 4; ++i) {
        af[i] = *(const short8*)(la + aoff[i]);
        bfv[i] = *(const short8*)(lb + boff[i]);
      }
      __builtin_amdgcn_s_setprio(1);
#pragma unroll
      for (int mi = 0; mi < 4; ++mi)
#pragma unroll
        for (int ni = 0; ni < 4; ++ni)
          acc[mi][ni] = mfma_bf16(af[mi], bfv[ni], acc[mi][ni]);
      __builtin_amdgcn_s_setprio(0);
      asm volatile("s_waitcnt vmcnt(8)" ::: "memory");
      __builtin_amdgcn_s_barrier();
      __builtin_amdgcn_sched_barrier(0);
    }
  }

#pragma unroll
  for (int mi = 0; mi < 4; ++mi) {
#pragma unroll
    for (int ni = 0; ni < 4; ++ni) {
      int gr0 = m0 + wm * 64 + mi * 16 + (g << 2);
      int gc = n0 + wn * 64 + ni * 16 + lr;
      float bv = b0[gc];
#pragma unroll
      for (int r = 0; r < 4; ++r)
        f_o[(size_t)(gr0 + r) * D_ + gc] = acc[mi][ni][r] + bv;
    }
  }
}

// ---------------- causal flash attention (v7: LPT grid, exp2 softmax) ----------------
__global__ __launch_bounds__(256, 2) void attn_fwd(
    const short* __restrict__ qb, const short* __restrict__ kb,
    const short* __restrict__ vtb, short* __restrict__ aob) {
  __shared__ __attribute__((aligned(16))) char kvlds[2][16384];

  int d = blockIdx.x;
  int bh = d & 31;
  int qt = 31 - (d >> 5);          // big jobs dispatch first
  int tid = threadIdx.x, w = tid >> 6, lane = tid & 63;
  int lr = lane & 15, g = lane >> 4;
  const short* Q  = qb  + (size_t)bh * T_ * HD_;
  const short* Kp = kb  + (size_t)bh * T_ * HD_;
  const short* Vt = vtb + (size_t)bh * HD_ * T_;
  const float scale2 = 0.12751879202f;  // (1/sqrt(128)) * log2(e)
  int b = bh >> 4, h = bh & 15;
  bool hi16 = (lane & 16) != 0;

  int oA = ((2 * w + 0) * 64 + lane) * 16;
  int oB = ((2 * w + 1) * 64 + lane) * 16;
  int rKA = oA >> 8, rKB = oB >> 8;
  size_t skA = (size_t)rKA * HD_ + (((oA & 255) ^ ((rKA & 7) << 4)) >> 1);
  size_t skB = (size_t)rKB * HD_ + (((oB & 255) ^ ((rKB & 7) << 4)) >> 1);
  int rVA = oA >> 6, rVB = oB >> 6;
  size_t svA = (size_t)rVA * T_ + (((oA & 63) ^ (((rVA >> 1) & 3) << 4)) >> 1);
  size_t svB = (size_t)rVB * T_ + (((oB & 63) ^ (((rVB >> 1) & 3) << 4)) >> 1);

  int q0 = qt * 64 + w * 16;
  int ntiles = 2 * qt + 2;

  {
    char* kd = &kvlds[0][0];
    char* vd = &kvlds[0][8192];
    gl_lds16(Kp + skA, kd + oA);
    gl_lds16(Kp + skB, kd + oB);
    gl_lds16(Vt + svA, vd + oA);
    gl_lds16(Vt + svB, vd + oB);
  }

  short8 qf[4];
#pragma unroll
  for (int kk = 0; kk < 4; ++kk)
    qf[kk] = *(const short8*)&Q[(size_t)(q0 + lr) * HD_ + kk * 32 + g * 8];

  f32x4 o[8] = {};
  float mrow = -1e30f, lrow = 0.f;
  __syncthreads();

#pragma unroll 1
  for (int t = 0; t < ntiles; ++t) {
    int kv0 = t * 32, buf = t & 1;
    if (t + 1 < ntiles) {
      char* kd = &kvlds[buf ^ 1][0];
      char* vd = &kvlds[buf ^ 1][8192];
      const short* Kn = Kp + (size_t)(kv0 + 32) * HD_;
      const short* Vn = Vt + (kv0 + 32);
      gl_lds16(Kn + skA, kd + oA);
      gl_lds16(Kn + skB, kd + oB);
      gl_lds16(Vn + svA, vd + oA);
      gl_lds16(Vn + svB, vd + oB);
    }
    if (kv0 < q0 + 16) {
      const char* kb_ = &kvlds[buf][0];
      const char* vb_ = &kvlds[buf][8192];
      short8 kf0[4], kf1[4], vf[8];
#pragma unroll
      for (int kk = 0; kk < 4; ++kk) {
        int cs = (kk * 64 + g * 16) ^ ((lr & 7) << 4);
        kf0[kk] = *(const short8*)(kb_ + (lr * 256 + cs));
        kf1[kk] = *(const short8*)(kb_ + ((16 + lr) * 256 + cs));
      }
#pragma unroll
      for (int f = 0; f < 8; ++f)
        vf[f] = *(const short8*)(vb_ + ((f * 16 + lr) * 64 +
                 ((g * 16) ^ (((lr >> 1) & 3) << 4))));

      f32x4 s0 = {}, s1 = {};
      __builtin_amdgcn_s_setprio(1);
#pragma unroll
      for (int kk = 0; kk < 4; ++kk) {
        s0 = mfma_bf16(kf0[kk], qf[kk], s0);
        s1 = mfma_bf16(kf1[kk], qf[kk], s1);
      }
      __builtin_amdgcn_s_setprio(0);

      float vv[8];
#pragma unroll
      for (int r = 0; r < 4; ++r) {
        vv[r] = s0[r] * scale2;
        vv[4 + r] = s1[r] * scale2;
      }
      if (kv0 + 31 > q0) {
        int qrow = q0 + lr;
#pragma unroll
        for (int r = 0; r < 4; ++r) {
          if (kv0 + 4 * g + r > qrow) vv[r] = -1e30f;
          if (kv0 + 16 + 4 * g + r > qrow) vv[4 + r] = -1e30f;
        }
      }

      float pm = vv[0];
#pragma unroll
      for (int i = 1; i < 8; ++i) pm = fmaxf(pm, vv[i]);
      { float2 tpm = sw32f(pm); pm = fmaxf(tpm.x, tpm.y); }
      { float2 tpm = sw16f(pm); pm = fmaxf(tpm.x, tpm.y); }

      bool rescale = !__all(pm - mrow <= 11.54f);
      float alpha = 1.0f;
      if (rescale) {
        float mnew = fmaxf(mrow, pm);
        alpha = ex2(mrow - mnew);
        mrow = mnew;
      }

      float p[8];
      float rs = 0.f;
#pragma unroll
      for (int i = 0; i < 8; ++i) { p[i] = ex2(vv[i] - mrow); rs += p[i]; }
      { float2 trs = sw32f(rs); rs = trs.x + trs.y; }
      { float2 trs = sw16f(rs); rs = trs.x + trs.y; }
      lrow = (rescale ? lrow * alpha : lrow) + rs;

      if (rescale) {
        float alr[4];
#pragma unroll
        for (int r = 0; r < 4; ++r) alr[r] = __shfl(alpha, 4 * g + r);
#pragma unroll
        for (int f = 0; f < 8; ++f)
#pragma unroll
          for (int r = 0; r < 4; ++r) o[f][r] *= alr[r];
      }

      unsigned w0 = cvtpk(p[0], p[1]), w1 = cvtpk(p[2], p[3]);
      unsigned w2 = cvtpk(p[4], p[5]), w3 = cvtpk(p[6], p[7]);
      unsigned e0, od0, e1, od1, e2, od2, e3, od3;
      sw16u(w0, e0, od0); sw16u(w1, e1, od1);
      sw16u(w2, e2, od2); sw16u(w3, e3, od3);
      unsigned F0 = e0,  S0 = e2;  pl32u(F0, S0);
      unsigned F1 = e1,  S1 = e3;  pl32u(F1, S1);
      unsigned F2 = od0, S2 = od2; pl32u(F2, S2);
      unsigned F3 = od1, S3 = od3; pl32u(F3, S3);
      uint32x4 paw = { hi16 ? S0 : F0, hi16 ? S1 : F1,
                       hi16 ? S2 : F2, hi16 ? S3 : F3 };
      short8 pa = __builtin_bit_cast(short8, paw);

      __builtin_amdgcn_s_setprio(1);
#pragma unroll
      for (int f = 0; f < 8; ++f) o[f] = mfma_bf16(pa, vf[f], o[f]);
      __builtin_amdgcn_s_setprio(0);
    }
    __syncthreads();
  }

  float inv = 1.0f / lrow;
  float invr[4];
#pragma unroll
  for (int r = 0; r < 4; ++r) invr[r] = __shfl(inv, 4 * g + r);
#pragma unroll
  for (int r = 0; r < 4; ++r) {
    int q = q0 + 4 * g + r;
    size_t rowoff = ((size_t)(b * T_ + q)) * D_ + h * HD_;
#pragma unroll
    for (int f = 0; f < 8; ++f)
      aob[rowoff + f * 16 + lr] = f2bf(o[f][r] * invr[r]);
  }
}

extern "C" void kernel_launch(void* const* d_in, const int* in_sizes, int n_in,
                              void* d_out, int out_size, void* d_ws, size_t ws_size,
                              hipStream_t stream) {
  const float* x  = (const float*)d_in[0];
  const float* Wq = (const float*)d_in[1];
  const float* bq = (const float*)d_in[2];
  const float* Wk = (const float*)d_in[3];
  const float* bk = (const float*)d_in[4];
  const float* Wv = (const float*)d_in[5];
  const float* bv = (const float*)d_in[6];
  const float* Wo = (const float*)d_in[7];
  const float* bo = (const float*)d_in[8];
  float* out  = (float*)d_out;
  float* kout = out + (size_t)M_ * D_;
  float* vout = kout + (size_t)M_ * D_;

  char* ws = (char*)d_ws;
  auto alloc = [&](size_t bytes) {
    char* p = ws;
    ws += (bytes + 255) & ~(size_t)255;
    return p;
  };
  short* xb    = (short*)alloc((size_t)M_ * D_ * 2);
  short* wqkvT = (short*)alloc((size_t)3 * D_ * D_ * 2);
  short* woT   = (short*)alloc((size_t)D_ * D_ * 2);
  short* qb    = (short*)alloc((size_t)M_ * D_ * 2);
  short* kb    = (short*)alloc((size_t)M_ * D_ * 2);
  short* vtb   = (short*)alloc((size_t)M_ * D_ * 2);
  short* aob = xb;  // reuse: xb dead after QKV GEMM

  cast_f32_bf16<<<2048, 256, 0, stream>>>(x, xb, M_ * D_ / 4);
  dim3 tb(32, 8);
  transpose_cast_w4<<<dim3(64, 64, 4), tb, 0, stream>>>(Wq, Wk, Wv, Wo, wqkvT, woT);

  gemm_qkv<<<1024, 256, 0, stream>>>(xb, wqkvT, bq, bk, bv, qb, kb, kout, vout, vtb);
  attn_fwd<<<1024, 256, 0, stream>>>(qb, kb, vtb, aob);
  gemm_rb<<<dim3(16, 32), 256, 0, stream>>>(aob, woT, bo, out);
}

// Round 16
// 243.321 us; speedup vs baseline: 1.2340x; 1.0920x over previous
//
#include <hip/hip_runtime.h>
#include <hip/hip_bf16.h>

#define B_ 2
#define T_ 2048
#define D_ 2048
#define H_ 16
#define HD_ 128
#define M_ 4096

typedef __attribute__((ext_vector_type(8))) short short8;
typedef __attribute__((ext_vector_type(8))) __bf16 bf16x8;
typedef __attribute__((ext_vector_type(4))) float f32x4;
typedef __attribute__((ext_vector_type(4))) unsigned uint32x4;

__device__ __forceinline__ short f2bf(float f) {
  unsigned u = __builtin_bit_cast(unsigned, f);
  u += 0x7fffu + ((u >> 16) & 1u);
  return (short)(u >> 16);
}

__device__ __forceinline__ unsigned cvtpk(float lo, float hi) {
  unsigned r;
  asm("v_cvt_pk_bf16_f32 %0, %1, %2" : "=v"(r) : "v"(lo), "v"(hi));
  return r;
}

__device__ __forceinline__ float ex2(float x) {
  float r;
  asm("v_exp_f32 %0, %1" : "=v"(r) : "v"(x));
  return r;
}

__device__ __forceinline__ void gl_lds16(const void* g, void* l) {
  __builtin_amdgcn_global_load_lds(
      (const __attribute__((address_space(1))) unsigned int*)g,
      (__attribute__((address_space(3))) unsigned int*)l, 16, 0, 0);
}

__device__ __forceinline__ f32x4 mfma_bf16(short8 a, short8 b, f32x4 c) {
  return __builtin_amdgcn_mfma_f32_16x16x32_bf16(
      __builtin_bit_cast(bf16x8, a), __builtin_bit_cast(bf16x8, b), c, 0, 0, 0);
}

__device__ __forceinline__ float2 sw16f(float x) {
  float a = x, bv;
  asm("v_mov_b32 %0, %1" : "=v"(bv) : "v"(x));
  asm("v_permlane16_swap_b32 %0, %1" : "+v"(a), "+v"(bv));
  return make_float2(a, bv);
}
__device__ __forceinline__ float2 sw32f(float x) {
  float a = x, bv;
  asm("v_mov_b32 %0, %1" : "=v"(bv) : "v"(x));
  asm("v_permlane32_swap_b32 %0, %1" : "+v"(a), "+v"(bv));
  return make_float2(a, bv);
}
__device__ __forceinline__ void sw16u(unsigned x, unsigned& e, unsigned& o) {
  unsigned a = x, bv;
  asm("v_mov_b32 %0, %1" : "=v"(bv) : "v"(x));
  asm("v_permlane16_swap_b32 %0, %1" : "+v"(a), "+v"(bv));
  e = a; o = bv;
}
__device__ __forceinline__ void pl32u(unsigned& a, unsigned& b) {
  asm("v_permlane32_swap_b32 %0, %1" : "+v"(a), "+v"(b));
}

// ---------------- fused prep: 4x W (K,N) f32 -> Wt (N,K) bf16, + x cast ----------------
// z in [0,3]: weight transpose; z == 4: x f32 -> bf16 cast (flattened grid).
__global__ void prep_fused(const float* __restrict__ Wq, const float* __restrict__ Wk,
                           const float* __restrict__ Wv, const float* __restrict__ Wo,
                           const float* __restrict__ x,
                           short* __restrict__ wqkv, short* __restrict__ wo,
                           short* __restrict__ xb) {
  int z = blockIdx.z;
  int tx = threadIdx.x, ty = threadIdx.y;
  if (z == 4) {
    int n4 = M_ * D_ / 4;
    int i = (blockIdx.y * 64 + blockIdx.x) * 256 + ty * 32 + tx;
    int stride = 64 * 64 * 256;
    for (; i < n4; i += stride) {
      float4 v = ((const float4*)x)[i];
      short4 s;
      s.x = f2bf(v.x); s.y = f2bf(v.y); s.z = f2bf(v.z); s.w = f2bf(v.w);
      ((short4*)xb)[i] = s;
    }
    return;
  }
  __shared__ float t[32][33];
  const float* W = z == 0 ? Wq : z == 1 ? Wk : z == 2 ? Wv : Wo;
  short* dst = z < 3 ? wqkv + (size_t)z * D_ * D_ : wo;
  int n0 = blockIdx.x * 32, k0 = blockIdx.y * 32;
#pragma unroll
  for (int j = 0; j < 4; ++j)
    t[ty + j * 8][tx] = W[(size_t)(k0 + ty + j * 8) * D_ + n0 + tx];
  __syncthreads();
#pragma unroll
  for (int j = 0; j < 4; ++j)
    dst[(size_t)(n0 + ty + j * 8) * D_ + k0 + tx] = f2bf(t[tx][ty + j * 8]);
}

// ---------------- 256x192 QKV GEMM (r8-best: 2-phase, exact 2-round grid) ----------------
// 512 thr = 8 waves (2M x 4N), per-wave 128x48 (acc[8][3]). BK=64 (two kh).
// ph0(t): read A(t,0)+B(t,0); stage A(t+1,1)+B(t+1); 24 MFMA; vmcnt(7); bar
// ph1(t): read A(t,1)+B(t,1); stage A(t+2,0);        24 MFMA; vmcnt(2); bar
__global__ __launch_bounds__(512, 2) void gemm_qkv(
    const short* __restrict__ A, const short* __restrict__ Bt,
    const float* __restrict__ b0, const float* __restrict__ b1,
    const float* __restrict__ b2,
    short* __restrict__ q_o, short* __restrict__ k_o,
    float* __restrict__ kf_o, float* __restrict__ vf_o,
    short* __restrict__ vt_o) {
  __shared__ __attribute__((aligned(16))) char lds[2][57344];  // 112 KB
  const int K = D_, NT = K / 64;

  int d = blockIdx.x;
  int lg = (d & 7) * 64 + (d >> 3);          // 512 = 8 XCD x 64, bijective
  int m0 = (lg & 15) * 256, n0 = (lg >> 4) * 192;

  int tid = threadIdx.x, lane = tid & 63, wid = tid >> 6;
  int wm = wid >> 2, wn = wid & 3;
  int lr = lane & 15, g = lane >> 4;

  int rowA = tid >> 2;
  int cA = ((((tid & 3) << 4) ^ (((rowA >> 1) & 3) << 4)) >> 1);
  const short* aS = A + (size_t)(m0 + rowA) * K + cA;
  int rowB = tid >> 3;
  int cB = ((((tid & 7) << 4) ^ ((rowB & 7) << 4)) >> 1);
  const short* bS = Bt + (size_t)(n0 + rowB) * K + cB;
  char* ldsb = (char*)lds;

  auto stageA = [&](int ts, int kh) {
    char* dst = ldsb + (ts & 1) * 57344 + kh * 16384 + tid * 16;
    const short* s = aS + ts * 64 + kh * 32;
    gl_lds16(s, dst);
    gl_lds16(s + (size_t)128 * K, dst + 8192);
  };
  auto stageB = [&](int ts) {
    char* dst = ldsb + (ts & 1) * 57344 + 32768 + tid * 16;
    const short* s = bS + ts * 64;
    gl_lds16(s, dst);
    gl_lds16(s + (size_t)64 * K, dst + 8192);
    gl_lds16(s + (size_t)128 * K, dst + 16384);
  };

  int swzA = (g * 16) ^ (((lr >> 1) & 3) << 4);
  int aoff = (wm * 128 + lr) * 64 + swzA;
  int boff0 = (wn * 48 + lr) * 128 + ((g * 16) ^ ((lr & 7) << 4));
  int boff1 = (wn * 48 + lr) * 128 + ((64 + g * 16) ^ ((lr & 7) << 4));

  f32x4 acc[8][3] = {};

  stageA(0, 0); stageB(0); stageA(0, 1); stageA(1, 0);
  asm volatile("s_waitcnt vmcnt(4)" ::: "memory");
  __builtin_amdgcn_s_barrier();
  __builtin_amdgcn_sched_barrier(0);

#pragma unroll 1
  for (int t = 0; t < NT; ++t) {
    const char* base = ldsb + (t & 1) * 57344;
    int t1 = (t + 1 < NT) ? t + 1 : NT - 1;
    int t2 = (t + 2 < NT) ? t + 2 : NT - 1;
    short8 afr[8], bfr[3];

    // ---- ph0: kh0 ----
#pragma unroll
    for (int mi = 0; mi < 8; ++mi) afr[mi] = *(const short8*)(base + aoff + mi * 1024);
#pragma unroll
    for (int ni = 0; ni < 3; ++ni) bfr[ni] = *(const short8*)(base + 32768 + boff0 + ni * 2048);
    stageA(t1, 1); stageB(t1);
    __builtin_amdgcn_s_setprio(1);
#pragma unroll
    for (int mi = 0; mi < 8; ++mi)
#pragma unroll
      for (int ni = 0; ni < 3; ++ni)
        acc[mi][ni] = mfma_bf16(afr[mi], bfr[ni], acc[mi][ni]);
    __builtin_amdgcn_s_setprio(0);
    asm volatile("s_waitcnt vmcnt(7)" ::: "memory");
    __builtin_amdgcn_s_barrier();
    __builtin_amdgcn_sched_barrier(0);

    // ---- ph1: kh1 ----
#pragma unroll
    for (int mi = 0; mi < 8; ++mi) afr[mi] = *(const short8*)(base + 16384 + aoff + mi * 1024);
#pragma unroll
    for (int ni = 0; ni < 3; ++ni) bfr[ni] = *(const short8*)(base + 32768 + boff1 + ni * 2048);
    stageA(t2, 0);
    __builtin_amdgcn_s_setprio(1);
#pragma unroll
    for (int mi = 0; mi < 8; ++mi)
#pragma unroll
      for (int ni = 0; ni < 3; ++ni)
        acc[mi][ni] = mfma_bf16(afr[mi], bfr[ni], acc[mi][ni]);
    __builtin_amdgcn_s_setprio(0);
    asm volatile("s_waitcnt vmcnt(2)" ::: "memory");
    __builtin_amdgcn_s_barrier();
    __builtin_amdgcn_sched_barrier(0);
  }

  // epilogue: per-ni region select (16-col groups never span q/k/v regions)
#pragma unroll
  for (int ni = 0; ni < 3; ++ni) {
    int gcb = n0 + wn * 48 + ni * 16;
    int region = gcb >> 11;
    int nc = (gcb & 2047) + lr;
    int hh = nc >> 7, hd = nc & 127;
    const float* bias = region == 0 ? b0 : region == 1 ? b1 : b2;
    float bv = bias[nc];
#pragma unroll
    for (int mi = 0; mi < 8; ++mi) {
      int gr0 = m0 + wm * 128 + mi * 16 + (g << 2);
      int bb = gr0 >> 11, tt0 = gr0 & 2047;
      size_t hbase = (size_t)(bb * H_ + hh);
      float v0 = acc[mi][ni][0] + bv;
      float v1 = acc[mi][ni][1] + bv;
      float v2 = acc[mi][ni][2] + bv;
      float v3 = acc[mi][ni][3] + bv;
      size_t ib = (hbase * T_ + tt0) * HD_ + hd;
      if (region == 0) {
        q_o[ib] = f2bf(v0); q_o[ib + HD_] = f2bf(v1);
        q_o[ib + 2 * HD_] = f2bf(v2); q_o[ib + 3 * HD_] = f2bf(v3);
      } else if (region == 1) {
        k_o[ib] = f2bf(v0); k_o[ib + HD_] = f2bf(v1);
        k_o[ib + 2 * HD_] = f2bf(v2); k_o[ib + 3 * HD_] = f2bf(v3);
        kf_o[ib] = v0; kf_o[ib + HD_] = v1;
        kf_o[ib + 2 * HD_] = v2; kf_o[ib + 3 * HD_] = v3;
      } else {
        vf_o[ib] = v0; vf_o[ib + HD_] = v1;
        vf_o[ib + 2 * HD_] = v2; vf_o[ib + 3 * HD_] = v3;
        short4 s4;
        s4.x = f2bf(v0); s4.y = f2bf(v1); s4.z = f2bf(v2); s4.w = f2bf(v3);
        *(short4*)&vt_o[(hbase * HD_ + hd) * T_ + tt0] = s4;
      }
    }
  }
}

// ---------------- ring-4 GEMM (Wo): C(M,2048) = A * Bt + bias, f32 out ----------------
__global__ __launch_bounds__(256, 2) void gemm_rb(
    const short* __restrict__ A, const short* __restrict__ Bt,
    const float* __restrict__ b0, float* __restrict__ f_o) {
  __shared__ __attribute__((aligned(16))) short lds[4][2][4096];
  const int K = D_, NT = K / 32;

  int nx = gridDim.x, nwg = nx * gridDim.y;
  int d = blockIdx.y * nx + blockIdx.x;
  int cpx = nwg >> 3;
  int lg = (d & 7) * cpx + (d >> 3);
  int m0 = (lg / nx) * 128, n0 = (lg % nx) * 128;

  int tid = threadIdx.x, lane = tid & 63, w = tid >> 6;
  int wm = w >> 1, wn = w & 1;
  int lr = lane & 15, g = lane >> 4;

  int o1 = tid * 16, o2 = 4096 + tid * 16;
  int row1 = tid >> 2, row2 = 64 + row1;
  int cb = (tid & 3) << 4;
  int c1 = (cb ^ (((row1 >> 1) & 3) << 4)) >> 1;
  int c2 = (cb ^ (((row2 >> 1) & 3) << 4)) >> 1;
  const short* aS1 = A + (size_t)(m0 + row1) * K + c1;
  const short* aS2 = A + (size_t)(m0 + row2) * K + c2;
  const short* bS1 = Bt + (size_t)(n0 + row1) * K + c1;
  const short* bS2 = Bt + (size_t)(n0 + row2) * K + c2;

  int aoff[4], boff[4];
#pragma unroll
  for (int i = 0; i < 4; ++i) {
    int ra = wm * 64 + i * 16 + lr;
    aoff[i] = ra * 64 + ((g * 16) ^ (((ra >> 1) & 3) << 4));
    int rb = wn * 64 + i * 16 + lr;
    boff[i] = rb * 64 + ((g * 16) ^ (((rb >> 1) & 3) << 4));
  }

  f32x4 acc[4][4] = {};

#pragma unroll
  for (int s = 0; s < 3; ++s) {
    char* la = (char*)&lds[s][0][0];
    char* lb = (char*)&lds[s][1][0];
    gl_lds16(aS1 + s * 32, la + o1);
    gl_lds16(aS2 + s * 32, la + o2);
    gl_lds16(bS1 + s * 32, lb + o1);
    gl_lds16(bS2 + s * 32, lb + o2);
  }
  asm volatile("s_waitcnt vmcnt(8)" ::: "memory");
  __builtin_amdgcn_s_barrier();
  __builtin_amdgcn_sched_barrier(0);

#pragma unroll 1
  for (int t4 = 0; t4 < NT; t4 += 4) {
#pragma unroll
    for (int p = 0; p < 4; ++p) {
      int t = t4 + p;
      {
        int ts = (t + 3 < NT) ? t + 3 : NT - 1;
        char* la = (char*)&lds[(p + 3) & 3][0][0];
        char* lb = (char*)&lds[(p + 3) & 3][1][0];
        gl_lds16(aS1 + ts * 32, la + o1);
        gl_lds16(aS2 + ts * 32, la + o2);
        gl_lds16(bS1 + ts * 32, lb + o1);
        gl_lds16(bS2 + ts * 32, lb + o2);
      }
      const char* la = (const char*)&lds[p][0][0];
      const char* lb = (const char*)&lds[p][1][0];
      short8 af[4], bfv[4];
#pragma unroll
      for (int i = 0; i < 4; ++i) {
        af[i] = *(const short8*)(la + aoff[i]);
        bfv[i] = *(const short8*)(lb + boff[i]);
      }
      __builtin_amdgcn_s_setprio(1);
#pragma unroll
      for (int mi = 0; mi < 4; ++mi)
#pragma unroll
        for (int ni = 0; ni < 4; ++ni)
          acc[mi][ni] = mfma_bf16(af[mi], bfv[ni], acc[mi][ni]);
      __builtin_amdgcn_s_setprio(0);
      asm volatile("s_waitcnt vmcnt(8)" ::: "memory");
      __builtin_amdgcn_s_barrier();
      __builtin_amdgcn_sched_barrier(0);
    }
  }

#pragma unroll
  for (int mi = 0; mi < 4; ++mi) {
#pragma unroll
    for (int ni = 0; ni < 4; ++ni) {
      int gr0 = m0 + wm * 64 + mi * 16 + (g << 2);
      int gc = n0 + wn * 64 + ni * 16 + lr;
      float bv = b0[gc];
#pragma unroll
      for (int r = 0; r < 4; ++r)
        f_o[(size_t)(gr0 + r) * D_ + gc] = acc[mi][ni][r] + bv;
    }
  }
}

// ---------------- causal flash attention (v7: LPT grid, exp2 softmax) ----------------
__global__ __launch_bounds__(256, 2) void attn_fwd(
    const short* __restrict__ qb, const short* __restrict__ kb,
    const short* __restrict__ vtb, short* __restrict__ aob) {
  __shared__ __attribute__((aligned(16))) char kvlds[2][16384];

  int d = blockIdx.x;
  int bh = d & 31;
  int qt = 31 - (d >> 5);          // big jobs dispatch first
  int tid = threadIdx.x, w = tid >> 6, lane = tid & 63;
  int lr = lane & 15, g = lane >> 4;
  const short* Q  = qb  + (size_t)bh * T_ * HD_;
  const short* Kp = kb  + (size_t)bh * T_ * HD_;
  const short* Vt = vtb + (size_t)bh * HD_ * T_;
  const float scale2 = 0.12751879202f;  // (1/sqrt(128)) * log2(e)
  int b = bh >> 4, h = bh & 15;
  bool hi16 = (lane & 16) != 0;

  int oA = ((2 * w + 0) * 64 + lane) * 16;
  int oB = ((2 * w + 1) * 64 + lane) * 16;
  int rKA = oA >> 8, rKB = oB >> 8;
  size_t skA = (size_t)rKA * HD_ + (((oA & 255) ^ ((rKA & 7) << 4)) >> 1);
  size_t skB = (size_t)rKB * HD_ + (((oB & 255) ^ ((rKB & 7) << 4)) >> 1);
  int rVA = oA >> 6, rVB = oB >> 6;
  size_t svA = (size_t)rVA * T_ + (((oA & 63) ^ (((rVA >> 1) & 3) << 4)) >> 1);
  size_t svB = (size_t)rVB * T_ + (((oB & 63) ^ (((rVB >> 1) & 3) << 4)) >> 1);

  int q0 = qt * 64 + w * 16;
  int ntiles = 2 * qt + 2;

  {
    char* kd = &kvlds[0][0];
    char* vd = &kvlds[0][8192];
    gl_lds16(Kp + skA, kd + oA);
    gl_lds16(Kp + skB, kd + oB);
    gl_lds16(Vt + svA, vd + oA);
    gl_lds16(Vt + svB, vd + oB);
  }

  short8 qf[4];
#pragma unroll
  for (int kk = 0; kk < 4; ++kk)
    qf[kk] = *(const short8*)&Q[(size_t)(q0 + lr) * HD_ + kk * 32 + g * 8];

  f32x4 o[8] = {};
  float mrow = -1e30f, lrow = 0.f;
  __syncthreads();

#pragma unroll 1
  for (int t = 0; t < ntiles; ++t) {
    int kv0 = t * 32, buf = t & 1;
    if (t + 1 < ntiles) {
      char* kd = &kvlds[buf ^ 1][0];
      char* vd = &kvlds[buf ^ 1][8192];
      const short* Kn = Kp + (size_t)(kv0 + 32) * HD_;
      const short* Vn = Vt + (kv0 + 32);
      gl_lds16(Kn + skA, kd + oA);
      gl_lds16(Kn + skB, kd + oB);
      gl_lds16(Vn + svA, vd + oA);
      gl_lds16(Vn + svB, vd + oB);
    }
    if (kv0 < q0 + 16) {
      const char* kb_ = &kvlds[buf][0];
      const char* vb_ = &kvlds[buf][8192];
      short8 kf0[4], kf1[4], vf[8];
#pragma unroll
      for (int kk = 0; kk < 4; ++kk) {
        int cs = (kk * 64 + g * 16) ^ ((lr & 7) << 4);
        kf0[kk] = *(const short8*)(kb_ + (lr * 256 + cs));
        kf1[kk] = *(const short8*)(kb_ + ((16 + lr) * 256 + cs));
      }
#pragma unroll
      for (int f = 0; f < 8; ++f)
        vf[f] = *(const short8*)(vb_ + ((f * 16 + lr) * 64 +
                 ((g * 16) ^ (((lr >> 1) & 3) << 4))));

      f32x4 s0 = {}, s1 = {};
      __builtin_amdgcn_s_setprio(1);
#pragma unroll
      for (int kk = 0; kk < 4; ++kk) {
        s0 = mfma_bf16(kf0[kk], qf[kk], s0);
        s1 = mfma_bf16(kf1[kk], qf[kk], s1);
      }
      __builtin_amdgcn_s_setprio(0);

      float vv[8];
#pragma unroll
      for (int r = 0; r < 4; ++r) {
        vv[r] = s0[r] * scale2;
        vv[4 + r] = s1[r] * scale2;
      }
      if (kv0 + 31 > q0) {
        int qrow = q0 + lr;
#pragma unroll
        for (int r = 0; r < 4; ++r) {
          if (kv0 + 4 * g + r > qrow) vv[r] = -1e30f;
          if (kv0 + 16 + 4 * g + r > qrow) vv[4 + r] = -1e30f;
        }
      }

      float pm = vv[0];
#pragma unroll
      for (int i = 1; i < 8; ++i) pm = fmaxf(pm, vv[i]);
      { float2 tpm = sw32f(pm); pm = fmaxf(tpm.x, tpm.y); }
      { float2 tpm = sw16f(pm); pm = fmaxf(tpm.x, tpm.y); }

      bool rescale = !__all(pm - mrow <= 11.54f);
      float alpha = 1.0f;
      if (rescale) {
        float mnew = fmaxf(mrow, pm);
        alpha = ex2(mrow - mnew);
        mrow = mnew;
      }

      float p[8];
      float rs = 0.f;
#pragma unroll
      for (int i = 0; i < 8; ++i) { p[i] = ex2(vv[i] - mrow); rs += p[i]; }
      { float2 trs = sw32f(rs); rs = trs.x + trs.y; }
      { float2 trs = sw16f(rs); rs = trs.x + trs.y; }
      lrow = (rescale ? lrow * alpha : lrow) + rs;

      if (rescale) {
        float alr[4];
#pragma unroll
        for (int r = 0; r < 4; ++r) alr[r] = __shfl(alpha, 4 * g + r);
#pragma unroll
        for (int f = 0; f < 8; ++f)
#pragma unroll
          for (int r = 0; r < 4; ++r) o[f][r] *= alr[r];
      }

      unsigned w0 = cvtpk(p[0], p[1]), w1 = cvtpk(p[2], p[3]);
      unsigned w2 = cvtpk(p[4], p[5]), w3 = cvtpk(p[6], p[7]);
      unsigned e0, od0, e1, od1, e2, od2, e3, od3;
      sw16u(w0, e0, od0); sw16u(w1, e1, od1);
      sw16u(w2, e2, od2); sw16u(w3, e3, od3);
      unsigned F0 = e0,  S0 = e2;  pl32u(F0, S0);
      unsigned F1 = e1,  S1 = e3;  pl32u(F1, S1);
      unsigned F2 = od0, S2 = od2; pl32u(F2, S2);
      unsigned F3 = od1, S3 = od3; pl32u(F3, S3);
      uint32x4 paw = { hi16 ? S0 : F0, hi16 ? S1 : F1,
                       hi16 ? S2 : F2, hi16 ? S3 : F3 };
      short8 pa = __builtin_bit_cast(short8, paw);

      __builtin_amdgcn_s_setprio(1);
#pragma unroll
      for (int f = 0; f < 8; ++f) o[f] = mfma_bf16(pa, vf[f], o[f]);
      __builtin_amdgcn_s_setprio(0);
    }
    __syncthreads();
  }

  float inv = 1.0f / lrow;
  float invr[4];
#pragma unroll
  for (int r = 0; r < 4; ++r) invr[r] = __shfl(inv, 4 * g + r);
#pragma unroll
  for (int r = 0; r < 4; ++r) {
    int q = q0 + 4 * g + r;
    size_t rowoff = ((size_t)(b * T_ + q)) * D_ + h * HD_;
#pragma unroll
    for (int f = 0; f < 8; ++f)
      aob[rowoff + f * 16 + lr] = f2bf(o[f][r] * invr[r]);
  }
}

extern "C" void kernel_launch(void* const* d_in, const int* in_sizes, int n_in,
                              void* d_out, int out_size, void* d_ws, size_t ws_size,
                              hipStream_t stream) {
  const float* x  = (const float*)d_in[0];
  const float* Wq = (const float*)d_in[1];
  const float* bq = (const float*)d_in[2];
  const float* Wk = (const float*)d_in[3];
  const float* bk = (const float*)d_in[4];
  const float* Wv = (const float*)d_in[5];
  const float* bv = (const float*)d_in[6];
  const float* Wo = (const float*)d_in[7];
  const float* bo = (const float*)d_in[8];
  float* out  = (float*)d_out;
  float* kout = out + (size_t)M_ * D_;
  float* vout = kout + (size_t)M_ * D_;

  char* ws = (char*)d_ws;
  auto alloc = [&](size_t bytes) {
    char* p = ws;
    ws += (bytes + 255) & ~(size_t)255;
    return p;
  };
  short* xb    = (short*)alloc((size_t)M_ * D_ * 2);
  short* wqkvT = (short*)alloc((size_t)3 * D_ * D_ * 2);
  short* woT   = (short*)alloc((size_t)D_ * D_ * 2);
  short* qb    = (short*)alloc((size_t)M_ * D_ * 2);
  short* kb    = (short*)alloc((size_t)M_ * D_ * 2);
  short* vtb   = (short*)alloc((size_t)M_ * D_ * 2);
  short* aob = xb;  // reuse: xb dead after QKV GEMM

  dim3 tb(32, 8);
  prep_fused<<<dim3(64, 64, 5), tb, 0, stream>>>(Wq, Wk, Wv, Wo, x, wqkvT, woT, xb);

  gemm_qkv<<<512, 512, 0, stream>>>(xb, wqkvT, bq, bk, bv, qb, kb, kout, vout, vtb);
  attn_fwd<<<1024, 256, 0, stream>>>(qb, kb, vtb, aob);
  gemm_rb<<<dim3(16, 32), 256, 0, stream>>>(aob, woT, bo, out);
}

// Round 17
// 240.765 us; speedup vs baseline: 1.2471x; 1.0106x over previous
//
#include <hip/hip_runtime.h>
#include <hip/hip_bf16.h>

#define B_ 2
#define T_ 2048
#define D_ 2048
#define H_ 16
#define HD_ 128
#define M_ 4096

typedef __attribute__((ext_vector_type(8))) short short8;
typedef __attribute__((ext_vector_type(8))) __bf16 bf16x8;
typedef __attribute__((ext_vector_type(4))) float f32x4;
typedef __attribute__((ext_vector_type(4))) unsigned uint32x4;

__device__ __forceinline__ short f2bf(float f) {
  unsigned u = __builtin_bit_cast(unsigned, f);
  u += 0x7fffu + ((u >> 16) & 1u);
  return (short)(u >> 16);
}

__device__ __forceinline__ unsigned cvtpk(float lo, float hi) {
  unsigned r;
  asm("v_cvt_pk_bf16_f32 %0, %1, %2" : "=v"(r) : "v"(lo), "v"(hi));
  return r;
}

__device__ __forceinline__ float ex2(float x) {
  float r;
  asm("v_exp_f32 %0, %1" : "=v"(r) : "v"(x));
  return r;
}

__device__ __forceinline__ void gl_lds16(const void* g, void* l) {
  __builtin_amdgcn_global_load_lds(
      (const __attribute__((address_space(1))) unsigned int*)g,
      (__attribute__((address_space(3))) unsigned int*)l, 16, 0, 0);
}

__device__ __forceinline__ f32x4 mfma_bf16(short8 a, short8 b, f32x4 c) {
  return __builtin_amdgcn_mfma_f32_16x16x32_bf16(
      __builtin_bit_cast(bf16x8, a), __builtin_bit_cast(bf16x8, b), c, 0, 0, 0);
}

__device__ __forceinline__ float2 sw16f(float x) {
  float a = x, bv;
  asm("v_mov_b32 %0, %1" : "=v"(bv) : "v"(x));
  asm("v_permlane16_swap_b32 %0, %1" : "+v"(a), "+v"(bv));
  return make_float2(a, bv);
}
__device__ __forceinline__ float2 sw32f(float x) {
  float a = x, bv;
  asm("v_mov_b32 %0, %1" : "=v"(bv) : "v"(x));
  asm("v_permlane32_swap_b32 %0, %1" : "+v"(a), "+v"(bv));
  return make_float2(a, bv);
}
__device__ __forceinline__ void sw16u(unsigned x, unsigned& e, unsigned& o) {
  unsigned a = x, bv;
  asm("v_mov_b32 %0, %1" : "=v"(bv) : "v"(x));
  asm("v_permlane16_swap_b32 %0, %1" : "+v"(a), "+v"(bv));
  e = a; o = bv;
}
__device__ __forceinline__ void pl32u(unsigned& a, unsigned& b) {
  asm("v_permlane32_swap_b32 %0, %1" : "+v"(a), "+v"(b));
}

// ---------------- fused prep: 4x W (K,N) f32 -> Wt (N,K) bf16, + x cast ----------------
__global__ void prep_fused(const float* __restrict__ Wq, const float* __restrict__ Wk,
                           const float* __restrict__ Wv, const float* __restrict__ Wo,
                           const float* __restrict__ x,
                           short* __restrict__ wqkv, short* __restrict__ wo,
                           short* __restrict__ xb) {
  int z = blockIdx.z;
  int tx = threadIdx.x, ty = threadIdx.y;
  if (z == 4) {
    int n4 = M_ * D_ / 4;
    int i = (blockIdx.y * 64 + blockIdx.x) * 256 + ty * 32 + tx;
    int stride = 64 * 64 * 256;
    for (; i < n4; i += stride) {
      float4 v = ((const float4*)x)[i];
      short4 s;
      s.x = f2bf(v.x); s.y = f2bf(v.y); s.z = f2bf(v.z); s.w = f2bf(v.w);
      ((short4*)xb)[i] = s;
    }
    return;
  }
  __shared__ float t[32][33];
  const float* W = z == 0 ? Wq : z == 1 ? Wk : z == 2 ? Wv : Wo;
  short* dst = z < 3 ? wqkv + (size_t)z * D_ * D_ : wo;
  int n0 = blockIdx.x * 32, k0 = blockIdx.y * 32;
#pragma unroll
  for (int j = 0; j < 4; ++j)
    t[ty + j * 8][tx] = W[(size_t)(k0 + ty + j * 8) * D_ + n0 + tx];
  __syncthreads();
#pragma unroll
  for (int j = 0; j < 4; ++j)
    dst[(size_t)(n0 + ty + j * 8) * D_ + k0 + tx] = f2bf(t[tx][ty + j * 8]);
}

// ---------------- 256x192 QKV GEMM (r8-best: 2-phase, exact 2-round grid) ----------------
__global__ __launch_bounds__(512, 2) void gemm_qkv(
    const short* __restrict__ A, const short* __restrict__ Bt,
    const float* __restrict__ b0, const float* __restrict__ b1,
    const float* __restrict__ b2,
    short* __restrict__ q_o, short* __restrict__ k_o,
    float* __restrict__ kf_o, float* __restrict__ vf_o,
    short* __restrict__ vt_o) {
  __shared__ __attribute__((aligned(16))) char lds[2][57344];  // 112 KB
  const int K = D_, NT = K / 64;

  int d = blockIdx.x;
  int lg = (d & 7) * 64 + (d >> 3);          // 512 = 8 XCD x 64, bijective
  int m0 = (lg & 15) * 256, n0 = (lg >> 4) * 192;

  int tid = threadIdx.x, lane = tid & 63, wid = tid >> 6;
  int wm = wid >> 2, wn = wid & 3;
  int lr = lane & 15, g = lane >> 4;

  int rowA = tid >> 2;
  int cA = ((((tid & 3) << 4) ^ (((rowA >> 1) & 3) << 4)) >> 1);
  const short* aS = A + (size_t)(m0 + rowA) * K + cA;
  int rowB = tid >> 3;
  int cB = ((((tid & 7) << 4) ^ ((rowB & 7) << 4)) >> 1);
  const short* bS = Bt + (size_t)(n0 + rowB) * K + cB;
  char* ldsb = (char*)lds;

  auto stageA = [&](int ts, int kh) {
    char* dst = ldsb + (ts & 1) * 57344 + kh * 16384 + tid * 16;
    const short* s = aS + ts * 64 + kh * 32;
    gl_lds16(s, dst);
    gl_lds16(s + (size_t)128 * K, dst + 8192);
  };
  auto stageB = [&](int ts) {
    char* dst = ldsb + (ts & 1) * 57344 + 32768 + tid * 16;
    const short* s = bS + ts * 64;
    gl_lds16(s, dst);
    gl_lds16(s + (size_t)64 * K, dst + 8192);
    gl_lds16(s + (size_t)128 * K, dst + 16384);
  };

  int swzA = (g * 16) ^ (((lr >> 1) & 3) << 4);
  int aoff = (wm * 128 + lr) * 64 + swzA;
  int boff0 = (wn * 48 + lr) * 128 + ((g * 16) ^ ((lr & 7) << 4));
  int boff1 = (wn * 48 + lr) * 128 + ((64 + g * 16) ^ ((lr & 7) << 4));

  f32x4 acc[8][3] = {};

  stageA(0, 0); stageB(0); stageA(0, 1); stageA(1, 0);
  asm volatile("s_waitcnt vmcnt(4)" ::: "memory");
  __builtin_amdgcn_s_barrier();
  __builtin_amdgcn_sched_barrier(0);

#pragma unroll 1
  for (int t = 0; t < NT; ++t) {
    const char* base = ldsb + (t & 1) * 57344;
    int t1 = (t + 1 < NT) ? t + 1 : NT - 1;
    int t2 = (t + 2 < NT) ? t + 2 : NT - 1;
    short8 afr[8], bfr[3];

    // ---- ph0: kh0 ----
#pragma unroll
    for (int mi = 0; mi < 8; ++mi) afr[mi] = *(const short8*)(base + aoff + mi * 1024);
#pragma unroll
    for (int ni = 0; ni < 3; ++ni) bfr[ni] = *(const short8*)(base + 32768 + boff0 + ni * 2048);
    stageA(t1, 1); stageB(t1);
    __builtin_amdgcn_s_setprio(1);
#pragma unroll
    for (int mi = 0; mi < 8; ++mi)
#pragma unroll
      for (int ni = 0; ni < 3; ++ni)
        acc[mi][ni] = mfma_bf16(afr[mi], bfr[ni], acc[mi][ni]);
    __builtin_amdgcn_s_setprio(0);
    asm volatile("s_waitcnt vmcnt(7)" ::: "memory");
    __builtin_amdgcn_s_barrier();
    __builtin_amdgcn_sched_barrier(0);

    // ---- ph1: kh1 ----
#pragma unroll
    for (int mi = 0; mi < 8; ++mi) afr[mi] = *(const short8*)(base + 16384 + aoff + mi * 1024);
#pragma unroll
    for (int ni = 0; ni < 3; ++ni) bfr[ni] = *(const short8*)(base + 32768 + boff1 + ni * 2048);
    stageA(t2, 0);
    __builtin_amdgcn_s_setprio(1);
#pragma unroll
    for (int mi = 0; mi < 8; ++mi)
#pragma unroll
      for (int ni = 0; ni < 3; ++ni)
        acc[mi][ni] = mfma_bf16(afr[mi], bfr[ni], acc[mi][ni]);
    __builtin_amdgcn_s_setprio(0);
    asm volatile("s_waitcnt vmcnt(2)" ::: "memory");
    __builtin_amdgcn_s_barrier();
    __builtin_amdgcn_sched_barrier(0);
  }

  // epilogue: per-ni region select (16-col groups never span q/k/v regions)
#pragma unroll
  for (int ni = 0; ni < 3; ++ni) {
    int gcb = n0 + wn * 48 + ni * 16;
    int region = gcb >> 11;
    int nc = (gcb & 2047) + lr;
    int hh = nc >> 7, hd = nc & 127;
    const float* bias = region == 0 ? b0 : region == 1 ? b1 : b2;
    float bv = bias[nc];
#pragma unroll
    for (int mi = 0; mi < 8; ++mi) {
      int gr0 = m0 + wm * 128 + mi * 16 + (g << 2);
      int bb = gr0 >> 11, tt0 = gr0 & 2047;
      size_t hbase = (size_t)(bb * H_ + hh);
      float v0 = acc[mi][ni][0] + bv;
      float v1 = acc[mi][ni][1] + bv;
      float v2 = acc[mi][ni][2] + bv;
      float v3 = acc[mi][ni][3] + bv;
      size_t ib = (hbase * T_ + tt0) * HD_ + hd;
      if (region == 0) {
        q_o[ib] = f2bf(v0); q_o[ib + HD_] = f2bf(v1);
        q_o[ib + 2 * HD_] = f2bf(v2); q_o[ib + 3 * HD_] = f2bf(v3);
      } else if (region == 1) {
        k_o[ib] = f2bf(v0); k_o[ib + HD_] = f2bf(v1);
        k_o[ib + 2 * HD_] = f2bf(v2); k_o[ib + 3 * HD_] = f2bf(v3);
        kf_o[ib] = v0; kf_o[ib + HD_] = v1;
        kf_o[ib + 2 * HD_] = v2; kf_o[ib + 3 * HD_] = v3;
      } else {
        vf_o[ib] = v0; vf_o[ib + HD_] = v1;
        vf_o[ib + 2 * HD_] = v2; vf_o[ib + 3 * HD_] = v3;
        short4 s4;
        s4.x = f2bf(v0); s4.y = f2bf(v1); s4.z = f2bf(v2); s4.w = f2bf(v3);
        *(short4*)&vt_o[(hbase * HD_ + hd) * T_ + tt0] = s4;
      }
    }
  }
}

// ---------------- Wo GEMM: r8 2-phase structure, 256x128, exact 1-round grid ----------------
// 512 thr = 8 waves (2M x 4N), per-wave 128x32 (acc[8][2]). BK=64 (two kh).
// LDS 96 KB = 2 buf x {A_kh0 16K | A_kh1 16K | B 16K}. Grid 256 = 16m x 16n,
// XCD-bijective (2 n-panels/XCD = 1 MB B in L2), exactly 1 block/CU.
// ph0(t): read A(t,0)+B(t,0); stage A(t+1,1)+B(t+1); 16 MFMA; vmcnt(6); bar
// ph1(t): read A(t,1)+B(t,1); stage A(t+2,0);        16 MFMA; vmcnt(2); bar
__global__ __launch_bounds__(512, 2) void gemm_wo(
    const short* __restrict__ A, const short* __restrict__ Bt,
    const float* __restrict__ b0, float* __restrict__ f_o) {
  __shared__ __attribute__((aligned(16))) char lds[2][49152];  // 96 KB
  const int K = D_, NT = K / 64;

  int d = blockIdx.x;
  int lg = (d & 7) * 32 + (d >> 3);          // 256 = 8 XCD x 32, bijective
  int m0 = (lg & 15) * 256, n0 = (lg >> 4) * 128;

  int tid = threadIdx.x, lane = tid & 63, wid = tid >> 6;
  int wm = wid >> 2, wn = wid & 3;
  int lr = lane & 15, g = lane >> 4;

  int rowA = tid >> 2;
  int cA = ((((tid & 3) << 4) ^ (((rowA >> 1) & 3) << 4)) >> 1);
  const short* aS = A + (size_t)(m0 + rowA) * K + cA;
  int rowB = tid >> 3;
  int cB = ((((tid & 7) << 4) ^ ((rowB & 7) << 4)) >> 1);
  const short* bS = Bt + (size_t)(n0 + rowB) * K + cB;
  char* ldsb = (char*)lds;

  auto stageA = [&](int ts, int kh) {
    char* dst = ldsb + (ts & 1) * 49152 + kh * 16384 + tid * 16;
    const short* s = aS + ts * 64 + kh * 32;
    gl_lds16(s, dst);
    gl_lds16(s + (size_t)128 * K, dst + 8192);
  };
  auto stageB = [&](int ts) {
    char* dst = ldsb + (ts & 1) * 49152 + 32768 + tid * 16;
    const short* s = bS + ts * 64;
    gl_lds16(s, dst);
    gl_lds16(s + (size_t)64 * K, dst + 8192);
  };

  int swzA = (g * 16) ^ (((lr >> 1) & 3) << 4);
  int aoff = (wm * 128 + lr) * 64 + swzA;
  int boff0 = (wn * 32 + lr) * 128 + ((g * 16) ^ ((lr & 7) << 4));
  int boff1 = (wn * 32 + lr) * 128 + ((64 + g * 16) ^ ((lr & 7) << 4));

  f32x4 acc[8][2] = {};

  stageA(0, 0); stageB(0); stageA(0, 1); stageA(1, 0);
  asm volatile("s_waitcnt vmcnt(2)" ::: "memory");
  __builtin_amdgcn_s_barrier();
  __builtin_amdgcn_sched_barrier(0);

#pragma unroll 1
  for (int t = 0; t < NT; ++t) {
    const char* base = ldsb + (t & 1) * 49152;
    int t1 = (t + 1 < NT) ? t + 1 : NT - 1;
    int t2 = (t + 2 < NT) ? t + 2 : NT - 1;
    short8 afr[8], bfr[2];

    // ---- ph0: kh0 ----
#pragma unroll
    for (int mi = 0; mi < 8; ++mi) afr[mi] = *(const short8*)(base + aoff + mi * 1024);
#pragma unroll
    for (int ni = 0; ni < 2; ++ni) bfr[ni] = *(const short8*)(base + 32768 + boff0 + ni * 2048);
    stageA(t1, 1); stageB(t1);
    __builtin_amdgcn_s_setprio(1);
#pragma unroll
    for (int mi = 0; mi < 8; ++mi)
#pragma unroll
      for (int ni = 0; ni < 2; ++ni)
        acc[mi][ni] = mfma_bf16(afr[mi], bfr[ni], acc[mi][ni]);
    __builtin_amdgcn_s_setprio(0);
    asm volatile("s_waitcnt vmcnt(6)" ::: "memory");
    __builtin_amdgcn_s_barrier();
    __builtin_amdgcn_sched_barrier(0);

    // ---- ph1: kh1 ----
#pragma unroll
    for (int mi = 0; mi < 8; ++mi) afr[mi] = *(const short8*)(base + 16384 + aoff + mi * 1024);
#pragma unroll
    for (int ni = 0; ni < 2; ++ni) bfr[ni] = *(const short8*)(base + 32768 + boff1 + ni * 2048);
    stageA(t2, 0);
    __builtin_amdgcn_s_setprio(1);
#pragma unroll
    for (int mi = 0; mi < 8; ++mi)
#pragma unroll
      for (int ni = 0; ni < 2; ++ni)
        acc[mi][ni] = mfma_bf16(afr[mi], bfr[ni], acc[mi][ni]);
    __builtin_amdgcn_s_setprio(0);
    asm volatile("s_waitcnt vmcnt(2)" ::: "memory");
    __builtin_amdgcn_s_barrier();
    __builtin_amdgcn_sched_barrier(0);
  }

  // epilogue: bias + f32 row-major store
#pragma unroll
  for (int ni = 0; ni < 2; ++ni) {
    int gc = n0 + wn * 32 + ni * 16 + lr;
    float bv = b0[gc];
#pragma unroll
    for (int mi = 0; mi < 8; ++mi) {
      int gr0 = m0 + wm * 128 + mi * 16 + (g << 2);
#pragma unroll
      for (int r = 0; r < 4; ++r)
        f_o[(size_t)(gr0 + r) * D_ + gc] = acc[mi][ni][r] + bv;
    }
  }
}

// ---------------- causal flash attention (v7: LPT grid, exp2 softmax) ----------------
__global__ __launch_bounds__(256, 2) void attn_fwd(
    const short* __restrict__ qb, const short* __restrict__ kb,
    const short* __restrict__ vtb, short* __restrict__ aob) {
  __shared__ __attribute__((aligned(16))) char kvlds[2][16384];

  int d = blockIdx.x;
  int bh = d & 31;
  int qt = 31 - (d >> 5);          // big jobs dispatch first
  int tid = threadIdx.x, w = tid >> 6, lane = tid & 63;
  int lr = lane & 15, g = lane >> 4;
  const short* Q  = qb  + (size_t)bh * T_ * HD_;
  const short* Kp = kb  + (size_t)bh * T_ * HD_;
  const short* Vt = vtb + (size_t)bh * HD_ * T_;
  const float scale2 = 0.12751879202f;  // (1/sqrt(128)) * log2(e)
  int b = bh >> 4, h = bh & 15;
  bool hi16 = (lane & 16) != 0;

  int oA = ((2 * w + 0) * 64 + lane) * 16;
  int oB = ((2 * w + 1) * 64 + lane) * 16;
  int rKA = oA >> 8, rKB = oB >> 8;
  size_t skA = (size_t)rKA * HD_ + (((oA & 255) ^ ((rKA & 7) << 4)) >> 1);
  size_t skB = (size_t)rKB * HD_ + (((oB & 255) ^ ((rKB & 7) << 4)) >> 1);
  int rVA = oA >> 6, rVB = oB >> 6;
  size_t svA = (size_t)rVA * T_ + (((oA & 63) ^ (((rVA >> 1) & 3) << 4)) >> 1);
  size_t svB = (size_t)rVB * T_ + (((oB & 63) ^ (((rVB >> 1) & 3) << 4)) >> 1);

  int q0 = qt * 64 + w * 16;
  int ntiles = 2 * qt + 2;

  {
    char* kd = &kvlds[0][0];
    char* vd = &kvlds[0][8192];
    gl_lds16(Kp + skA, kd + oA);
    gl_lds16(Kp + skB, kd + oB);
    gl_lds16(Vt + svA, vd + oA);
    gl_lds16(Vt + svB, vd + oB);
  }

  short8 qf[4];
#pragma unroll
  for (int kk = 0; kk < 4; ++kk)
    qf[kk] = *(const short8*)&Q[(size_t)(q0 + lr) * HD_ + kk * 32 + g * 8];

  f32x4 o[8] = {};
  float mrow = -1e30f, lrow = 0.f;
  __syncthreads();

#pragma unroll 1
  for (int t = 0; t < ntiles; ++t) {
    int kv0 = t * 32, buf = t & 1;
    if (t + 1 < ntiles) {
      char* kd = &kvlds[buf ^ 1][0];
      char* vd = &kvlds[buf ^ 1][8192];
      const short* Kn = Kp + (size_t)(kv0 + 32) * HD_;
      const short* Vn = Vt + (kv0 + 32);
      gl_lds16(Kn + skA, kd + oA);
      gl_lds16(Kn + skB, kd + oB);
      gl_lds16(Vn + svA, vd + oA);
      gl_lds16(Vn + svB, vd + oB);
    }
    if (kv0 < q0 + 16) {
      const char* kb_ = &kvlds[buf][0];
      const char* vb_ = &kvlds[buf][8192];
      short8 kf0[4], kf1[4], vf[8];
#pragma unroll
      for (int kk = 0; kk < 4; ++kk) {
        int cs = (kk * 64 + g * 16) ^ ((lr & 7) << 4);
        kf0[kk] = *(const short8*)(kb_ + (lr * 256 + cs));
        kf1[kk] = *(const short8*)(kb_ + ((16 + lr) * 256 + cs));
      }
#pragma unroll
      for (int f = 0; f < 8; ++f)
        vf[f] = *(const short8*)(vb_ + ((f * 16 + lr) * 64 +
                 ((g * 16) ^ (((lr >> 1) & 3) << 4))));

      f32x4 s0 = {}, s1 = {};
      __builtin_amdgcn_s_setprio(1);
#pragma unroll
      for (int kk = 0; kk < 4; ++kk) {
        s0 = mfma_bf16(kf0[kk], qf[kk], s0);
        s1 = mfma_bf16(kf1[kk], qf[kk], s1);
      }
      __builtin_amdgcn_s_setprio(0);

      float vv[8];
#pragma unroll
      for (int r = 0; r < 4; ++r) {
        vv[r] = s0[r] * scale2;
        vv[4 + r] = s1[r] * scale2;
      }
      if (kv0 + 31 > q0) {
        int qrow = q0 + lr;
#pragma unroll
        for (int r = 0; r < 4; ++r) {
          if (kv0 + 4 * g + r > qrow) vv[r] = -1e30f;
          if (kv0 + 16 + 4 * g + r > qrow) vv[4 + r] = -1e30f;
        }
      }

      float pm = vv[0];
#pragma unroll
      for (int i = 1; i < 8; ++i) pm = fmaxf(pm, vv[i]);
      { float2 tpm = sw32f(pm); pm = fmaxf(tpm.x, tpm.y); }
      { float2 tpm = sw16f(pm); pm = fmaxf(tpm.x, tpm.y); }

      bool rescale = !__all(pm - mrow <= 11.54f);
      float alpha = 1.0f;
      if (rescale) {
        float mnew = fmaxf(mrow, pm);
        alpha = ex2(mrow - mnew);
        mrow = mnew;
      }

      float p[8];
      float rs = 0.f;
#pragma unroll
      for (int i = 0; i < 8; ++i) { p[i] = ex2(vv[i] - mrow); rs += p[i]; }
      { float2 trs = sw32f(rs); rs = trs.x + trs.y; }
      { float2 trs = sw16f(rs); rs = trs.x + trs.y; }
      lrow = (rescale ? lrow * alpha : lrow) + rs;

      if (rescale) {
        float alr[4];
#pragma unroll
        for (int r = 0; r < 4; ++r) alr[r] = __shfl(alpha, 4 * g + r);
#pragma unroll
        for (int f = 0; f < 8; ++f)
#pragma unroll
          for (int r = 0; r < 4; ++r) o[f][r] *= alr[r];
      }

      unsigned w0 = cvtpk(p[0], p[1]), w1 = cvtpk(p[2], p[3]);
      unsigned w2 = cvtpk(p[4], p[5]), w3 = cvtpk(p[6], p[7]);
      unsigned e0, od0, e1, od1, e2, od2, e3, od3;
      sw16u(w0, e0, od0); sw16u(w1, e1, od1);
      sw16u(w2, e2, od2); sw16u(w3, e3, od3);
      unsigned F0 = e0,  S0 = e2;  pl32u(F0, S0);
      unsigned F1 = e1,  S1 = e3;  pl32u(F1, S1);
      unsigned F2 = od0, S2 = od2; pl32u(F2, S2);
      unsigned F3 = od1, S3 = od3; pl32u(F3, S3);
      uint32x4 paw = { hi16 ? S0 : F0, hi16 ? S1 : F1,
                       hi16 ? S2 : F2, hi16 ? S3 : F3 };
      short8 pa = __builtin_bit_cast(short8, paw);

      __builtin_amdgcn_s_setprio(1);
#pragma unroll
      for (int f = 0; f < 8; ++f) o[f] = mfma_bf16(pa, vf[f], o[f]);
      __builtin_amdgcn_s_setprio(0);
    }
    __syncthreads();
  }

  float inv = 1.0f / lrow;
  float invr[4];
#pragma unroll
  for (int r = 0; r < 4; ++r) invr[r] = __shfl(inv, 4 * g + r);
#pragma unroll
  for (int r = 0; r < 4; ++r) {
    int q = q0 + 4 * g + r;
    size_t rowoff = ((size_t)(b * T_ + q)) * D_ + h * HD_;
#pragma unroll
    for (int f = 0; f < 8; ++f)
      aob[rowoff + f * 16 + lr] = f2bf(o[f][r] * invr[r]);
  }
}

extern "C" void kernel_launch(void* const* d_in, const int* in_sizes, int n_in,
                              void* d_out, int out_size, void* d_ws, size_t ws_size,
                              hipStream_t stream) {
  const float* x  = (const float*)d_in[0];
  const float* Wq = (const float*)d_in[1];
  const float* bq = (const float*)d_in[2];
  const float* Wk = (const float*)d_in[3];
  const float* bk = (const float*)d_in[4];
  const float* Wv = (const float*)d_in[5];
  const float* bv = (const float*)d_in[6];
  const float* Wo = (const float*)d_in[7];
  const float* bo = (const float*)d_in[8];
  float* out  = (float*)d_out;
  float* kout = out + (size_t)M_ * D_;
  float* vout = kout + (size_t)M_ * D_;

  char* ws = (char*)d_ws;
  auto alloc = [&](size_t bytes) {
    char* p = ws;
    ws += (bytes + 255) & ~(size_t)255;
    return p;
  };
  short* xb    = (short*)alloc((size_t)M_ * D_ * 2);
  short* wqkvT = (short*)alloc((size_t)3 * D_ * D_ * 2);
  short* woT   = (short*)alloc((size_t)D_ * D_ * 2);
  short* qb    = (short*)alloc((size_t)M_ * D_ * 2);
  short* kb    = (short*)alloc((size_t)M_ * D_ * 2);
  short* vtb   = (short*)alloc((size_t)M_ * D_ * 2);
  short* aob = xb;  // reuse: xb dead after QKV GEMM

  dim3 tb(32, 8);
  prep_fused<<<dim3(64, 64, 5), tb, 0, stream>>>(Wq, Wk, Wv, Wo, x, wqkvT, woT, xb);

  gemm_qkv<<<512, 512, 0, stream>>>(xb, wqkvT, bq, bk, bv, qb, kb, kout, vout, vtb);
  attn_fwd<<<1024, 256, 0, stream>>>(qb, kb, vtb, aob);
  gemm_wo<<<256, 512, 0, stream>>>(aob, woT, bo, out);
}